// Round 9
// baseline (1014.442 us; speedup 1.0000x reference)
//
#include <hip/hip_runtime.h>
#include <stdint.h>

#define DEVI static __device__ __forceinline__

typedef unsigned short u16;
typedef unsigned int u32;
typedef __attribute__((ext_vector_type(8))) short short8;
typedef __attribute__((ext_vector_type(4))) float f32x4;
typedef __attribute__((ext_vector_type(4))) unsigned short ushort4_t;

#define BB 4
#define SS 4096
#define DD 1024
#define HH 16
#define HDD 64
#define MM 256
#define BHN 64

DEVI u16 f2bf(float f) {
    u32 u = __float_as_uint(f);
    u += 0x7fffu + ((u >> 16) & 1u);
    return (u16)(u >> 16);
}
DEVI float bf2f(u16 h) { return __uint_as_float(((u32)h) << 16); }

typedef __attribute__((address_space(1))) const unsigned int as1_u32;
typedef __attribute__((address_space(3))) unsigned int as3_u32;
DEVI void load_lds16(const void* g, void* lds) {
    __builtin_amdgcn_global_load_lds((as1_u32*)g, (as3_u32*)lds, 16, 0, 0);
}

// ---------------- conversion kernels ----------------

__global__ void conv_bf16(const float* __restrict__ src, u16* __restrict__ dst, int n4) {
    int i = blockIdx.x * 256 + threadIdx.x;
    if (i < n4) {
        float4 v = reinterpret_cast<const float4*>(src)[i];
        ushort4_t o = { f2bf(v.x), f2bf(v.y), f2bf(v.z), f2bf(v.w) };
        reinterpret_cast<ushort4_t*>(dst)[i] = o;
    }
}

__global__ void conv_w(const float* __restrict__ Wq, const float* __restrict__ Wk,
                       const float* __restrict__ Wv, u16* __restrict__ Wt) {
    __shared__ float tile[64][65];
    const int jt = blockIdx.x, kt = blockIdx.y;
    const float* src = (jt < 16) ? Wq : (jt < 32) ? Wk : Wv;
    const int j0 = (jt & 15) * 64, k0 = kt * 64;
    const int t = threadIdx.x;
    for (int i = 0; i < 16; ++i) {
        int lin = t + i * 256;
        int kl = lin >> 6, jl = lin & 63;
        tile[kl][jl] = src[(size_t)(k0 + kl) * DD + j0 + jl];
    }
    __syncthreads();
    const int jg0 = jt * 64;
    for (int i = 0; i < 16; ++i) {
        int lin = t + i * 256;
        int jl = lin >> 6, kl = lin & 63;
        Wt[(size_t)(jg0 + jl) * DD + k0 + kl] = f2bf(tile[kl][jl]);
    }
}

// ---------------- QKV GEMM: R4 schedule, BK=32, 64KB LDS -> 2 blocks/CU ----------------
// BM=BN=256, BK=32, 32 k-tiles; 512 thr = 8 waves (2M x 4N); per-wave 128x64.
// LDS = 2 x (A 16KB + B 16KB) = 64KB double-buffered; drain vmcnt(0) at tile boundary
// (covered by the co-resident block). Layout: paired rows [r>>1][(r&1)*32+k], 128B
// lines, XOR ^((pair&7)<<4). All pieces bench-proven (R4 schedule, R5 layout).
__global__ __launch_bounds__(512, 4) void gemm1_bk32(
    const u16* __restrict__ Xbf, const u16* __restrict__ Wt,
    const float* __restrict__ bq, const float* __restrict__ bk, const float* __restrict__ bv,
    const float* __restrict__ mask,
    u16* __restrict__ Qh, u16* __restrict__ Kh, u16* __restrict__ Vt,
    float* __restrict__ dq, float* __restrict__ dk)
{
    extern __shared__ __align__(16) char smem[];
    const int tid = threadIdx.x, l = tid & 63, wv = tid >> 6;
    const int wm = wv >> 2, wn = wv & 3;
    const int bid = blockIdx.x;
    const int xcd = bid & 7, i6 = bid >> 3;          // 768 = 8 * 96, bijective
    const int bx = xcd * 8 + i6 / 12, by = i6 % 12;
    const int row0 = bx * 256, col0 = by * 256;

    // staging source decode (pre-swizzled global source, linear LDS dest) [R5-proven]
    int sA[2];
#pragma unroll
    for (int j = 0; j < 2; ++j) {
        const int o = j * 8192 + tid * 16;
        const int R = o >> 7;
        const int logpos = (o & 127) ^ ((R & 7) << 4);
        const int r = 2 * R + (logpos >> 6);
        const int c8 = (logpos >> 4) & 3;
        sA[j] = r * DD + c8 * 8;
    }
    const size_t xbase = (size_t)row0 * DD;
    const size_t wbase = (size_t)col0 * DD;

    #define ABUF(b) ((char*)smem + (b) * 16384)
    #define BBUF(b) ((char*)smem + 32768 + (b) * 16384)
    #define STA(b, kt, j) load_lds16(Xbf + xbase + (kt) * 32 + sA[j], ABUF(b) + (j) * 8192 + wv * 1024)
    #define STB(b, kt, j) load_lds16(Wt + wbase + (kt) * 32 + sA[j], BBUF(b) + (j) * 8192 + wv * 1024)

    // prologue: tile 0 -> buf 0
    STA(0, 0, 0); STA(0, 0, 1); STB(0, 0, 0); STB(0, 0, 1);
    asm volatile("s_waitcnt vmcnt(0)" ::: "memory");
    __builtin_amdgcn_s_barrier();
    __builtin_amdgcn_sched_barrier(0);

    f32x4 acc[8][4] = {};
    const int hl = (l & 15) >> 1;
    const int xorc = hl << 4;
    const int pa = ((wm * 64 + hl) * 128 + (l & 1) * 64 + (l >> 4) * 16) ^ xorc;
    const int pb = ((wn * 32 + hl) * 128 + (l & 1) * 64 + (l >> 4) * 16) ^ xorc;

    for (int kt = 0; kt < 32; ++kt) {
        const int p = kt & 1, pn = p ^ 1;
        const bool more = (kt + 1) < 32;
        short8 bfr[4];
#pragma unroll
        for (int q = 0; q < 4; ++q) {
            if (more) {                              // stage tile kt+1 spread over sub-phases
                if (q == 0)      STA(pn, kt + 1, 0);
                else if (q == 1) STA(pn, kt + 1, 1);
                else if (q == 2) STB(pn, kt + 1, 0);
                else             STB(pn, kt + 1, 1);
            }
            if (q == 0) {
#pragma unroll
                for (int nf = 0; nf < 4; ++nf)
                    bfr[nf] = *(const short8*)(BBUF(p) + pb + nf * 1024);
            }
            short8 a[2];
#pragma unroll
            for (int i = 0; i < 2; ++i)
                a[i] = *(const short8*)(ABUF(p) + pa + (q * 2 + i) * 1024);
            __builtin_amdgcn_s_setprio(1);
#pragma unroll
            for (int i = 0; i < 2; ++i)
#pragma unroll
                for (int nf = 0; nf < 4; ++nf)
                    acc[q * 2 + i][nf] = __builtin_amdgcn_mfma_f32_16x16x32_bf16(a[i], bfr[nf], acc[q * 2 + i][nf], 0, 0, 0);
            __builtin_amdgcn_s_setprio(0);
            __builtin_amdgcn_sched_barrier(0);
        }
        asm volatile("s_waitcnt vmcnt(0)" ::: "memory");
        __builtin_amdgcn_s_barrier();
        __builtin_amdgcn_sched_barrier(0);
    }

    // ---------- fused epilogue (identical to R4/R7) ----------
    const int region = by >> 2;
    const int h = ((by & 3) << 2) + wn;
    const int rg = row0 + wm * 128;
    const int b = rg >> 12;
    const int sb = rg & 4095;
    const size_t bh = (size_t)(b * HH + h);
    const int dd = l & 15;
    const int jbase = ((by & 3) << 8) + wn * 64;

    if (region == 0) {
        float bias[4];
#pragma unroll
        for (int nf = 0; nf < 4; ++nf) bias[nf] = bq[jbase + nf * 16 + dd];
#pragma unroll
        for (int mf = 0; mf < 8; ++mf) {
            float ds4[4];
#pragma unroll
            for (int g = 0; g < 4; ++g) {
                const int s = sb + mf * 16 + ((l >> 4) << 2) + g;
                float dsum = 0.f;
#pragma unroll
                for (int nf = 0; nf < 4; ++nf) {
                    u16 hv = f2bf((acc[mf][nf][g] + bias[nf]) * 0.125f);
                    Qh[(bh * SS + s) * HDD + nf * 16 + dd] = hv;
                    float fv = bf2f(hv);
                    dsum += fv * fv;
                }
                dsum += __shfl_xor(dsum, 1);
                dsum += __shfl_xor(dsum, 2);
                dsum += __shfl_xor(dsum, 4);
                dsum += __shfl_xor(dsum, 8);
                ds4[g] = 0.5f * dsum;
            }
            if (dd == 0)
                *(float4*)(dq + bh * SS + sb + mf * 16 + ((l >> 4) << 2)) =
                    make_float4(ds4[0], ds4[1], ds4[2], ds4[3]);
        }
    } else if (region == 1) {
        float bias[4];
#pragma unroll
        for (int nf = 0; nf < 4; ++nf) bias[nf] = bk[jbase + nf * 16 + dd];
#pragma unroll
        for (int mf = 0; mf < 8; ++mf) {
            float ds4[4];
#pragma unroll
            for (int g = 0; g < 4; ++g) {
                const int s = sb + mf * 16 + ((l >> 4) << 2) + g;
                const float m = mask[b * SS + s];
                float dsum = 0.f;
#pragma unroll
                for (int nf = 0; nf < 4; ++nf) {
                    u16 hv = f2bf((acc[mf][nf][g] + bias[nf]) * m * 0.125f);
                    Kh[(bh * SS + s) * HDD + nf * 16 + dd] = hv;
                    float fv = bf2f(hv);
                    dsum += fv * fv;
                }
                dsum += __shfl_xor(dsum, 1);
                dsum += __shfl_xor(dsum, 2);
                dsum += __shfl_xor(dsum, 4);
                dsum += __shfl_xor(dsum, 8);
                ds4[g] = 0.5f * dsum;
            }
            if (dd == 0)
                *(float4*)(dk + bh * SS + sb + mf * 16 + ((l >> 4) << 2)) =
                    make_float4(ds4[0], ds4[1], ds4[2], ds4[3]);
        }
    } else {
        float bias[4];
#pragma unroll
        for (int nf = 0; nf < 4; ++nf) bias[nf] = bv[jbase + nf * 16 + dd];
#pragma unroll
        for (int mf = 0; mf < 8; ++mf) {
            const int s0 = sb + mf * 16 + ((l >> 4) << 2);
#pragma unroll
            for (int nf = 0; nf < 4; ++nf) {
                ushort4_t pk;
#pragma unroll
                for (int g = 0; g < 4; ++g) {
                    const float m = mask[b * SS + s0 + g];
                    pk[g] = f2bf((acc[mf][nf][g] + bias[nf]) * m);
                }
                *(ushort4_t*)(Vt + (bh * HDD + nf * 16 + dd) * SS + s0) = pk;
            }
        }
    }
    #undef ABUF
    #undef BBUF
    #undef STA
    #undef STB
}

// ---------------- kv_fused v5: single-pass online-max (flash-style) ----------------
__global__ __launch_bounds__(256, 2) void kv_fused(
    const u16* __restrict__ Kh, const u16* __restrict__ Vt,
    const u16* __restrict__ projb, const float* __restrict__ dk,
    float* __restrict__ kv_part, float* __restrict__ ksum_part,
    float* __restrict__ vsum_part, float* __restrict__ lstab)
{
    extern __shared__ __align__(16) char ksm[];
    #define KLDS(b) ((char*)ksm + (b) * 8192)
    #define VLDS(b) ((char*)ksm + 24576 + (b) * 8192)
    u16* Kp = (u16*)((char*)ksm + 49152);
    const int tid = threadIdx.x, l = tid & 63, wv = tid >> 6;
    const int ck = blockIdx.x, bh = blockIdx.y;
    short8 pb[4][2];
#pragma unroll
    for (int nf = 0; nf < 4; ++nf)
#pragma unroll
        for (int ks = 0; ks < 2; ++ks)
            pb[nf][ks] = *(const short8*)(projb + (wv * 64 + nf * 16 + (l & 15)) * HDD + ks * 32 + (l >> 4) * 8);
    const size_t sbase = (size_t)bh * SS + ck * 512;

    #define KSTAGE(buf, it8) do { \
        const int s0_ = (it8) * 64; \
        _Pragma("unroll") \
        for (int c = 0; c < 2; ++c) { \
            const int rb = wv * 16 + c * 8; \
            const int r = rb + (l >> 3); \
            const int sc = ((l & 7) ^ (r & 7)) * 8; \
            load_lds16(Kh + (sbase + s0_ + r) * HDD + sc, KLDS(buf) + rb * 128); \
        } \
    } while (0)
    #define VSTAGE(buf, it8) do { \
        const int s0_ = (it8) * 64; \
        _Pragma("unroll") \
        for (int c = 0; c < 2; ++c) { \
            const int rb = wv * 16 + c * 8; \
            const int r = rb + (l >> 3); \
            const int sc = ((l & 7) ^ (r & 7)) * 8; \
            load_lds16(Vt + ((size_t)bh * HDD + r) * SS + ck * 512 + s0_ + sc, VLDS(buf) + rb * 128); \
        } \
    } while (0)

    float mrun = -3.0e38f;
    f32x4 acc[4][4] = {};
    float ksc[4] = {0.f, 0.f, 0.f, 0.f};
    float vsc[4] = {0.f, 0.f, 0.f, 0.f};
    KSTAGE(0, 0); VSTAGE(0, 0);
    for (int it = 0; it < 8; ++it) {
        if (it + 1 < 8) {
            KSTAGE((it + 1) % 3, it + 1);
            VSTAGE((it + 1) % 3, it + 1);
            asm volatile("s_waitcnt vmcnt(4)" ::: "memory");
        } else {
            asm volatile("s_waitcnt vmcnt(0)" ::: "memory");
        }
        __syncthreads();
        const int bs = it % 3;
        const int s0 = it * 64;
        f32x4 u4[4][4];
#pragma unroll
        for (int sf = 0; sf < 4; ++sf) {
#pragma unroll
            for (int nf = 0; nf < 4; ++nf) u4[sf][nf] = (f32x4){0.f, 0.f, 0.f, 0.f};
            const int s = sf * 16 + (l & 15);
#pragma unroll
            for (int ks = 0; ks < 2; ++ks) {
                short8 ak = *(const short8*)(KLDS(bs) + s * 128 + ((ks * 64 + (l >> 4) * 16) ^ ((s & 7) << 4)));
#pragma unroll
                for (int nf = 0; nf < 4; ++nf)
                    u4[sf][nf] = __builtin_amdgcn_mfma_f32_16x16x32_bf16(ak, pb[nf][ks], u4[sf][nf], 0, 0, 0);
            }
        }
        float pmax = -3.0e38f;
#pragma unroll
        for (int sf = 0; sf < 4; ++sf)
#pragma unroll
            for (int nf = 0; nf < 4; ++nf)
#pragma unroll
                for (int g = 0; g < 4; ++g) pmax = fmaxf(pmax, u4[sf][nf][g]);
#pragma unroll
        for (int o = 1; o < 64; o <<= 1) pmax = fmaxf(pmax, __shfl_xor(pmax, o));
        if (pmax > mrun) {                       // wave-uniform
            const float fac = __expf(mrun - pmax);
            mrun = pmax;
#pragma unroll
            for (int mf = 0; mf < 4; ++mf)
#pragma unroll
                for (int nf = 0; nf < 4; ++nf)
#pragma unroll
                    for (int g = 0; g < 4; ++g) acc[mf][nf][g] *= fac;
#pragma unroll
            for (int nf = 0; nf < 4; ++nf) ksc[nf] *= fac;
        }
#pragma unroll
        for (int sf = 0; sf < 4; ++sf) {
            const int srow = sf * 16 + (l >> 4) * 4;
            const float4 dkv = *(const float4*)(dk + sbase + s0 + srow);
#pragma unroll
            for (int nf = 0; nf < 4; ++nf) {
                const int m = wv * 64 + nf * 16 + (l & 15);
                u16 h0 = f2bf(__expf(u4[sf][nf][0] - dkv.x - mrun));
                u16 h1 = f2bf(__expf(u4[sf][nf][1] - dkv.y - mrun));
                u16 h2 = f2bf(__expf(u4[sf][nf][2] - dkv.z - mrun));
                u16 h3 = f2bf(__expf(u4[sf][nf][3] - dkv.w - mrun));
                ksc[nf] += bf2f(h0) + bf2f(h1) + bf2f(h2) + bf2f(h3);
                uint2 w; w.x = (u32)h0 | ((u32)h1 << 16); w.y = (u32)h2 | ((u32)h3 << 16);
                *(uint2*)((char*)Kp + m * 128 + ((srow * 2) ^ ((m & 7) << 4))) = w;
            }
        }
        __syncthreads();
#pragma unroll
        for (int ks = 0; ks < 2; ++ks) {
            short8 am[4], bv8[4];
#pragma unroll
            for (int mf = 0; mf < 4; ++mf) {
                const int m = wv * 64 + mf * 16 + (l & 15);
                am[mf] = *(const short8*)((const char*)Kp + m * 128 + ((ks * 64 + (l >> 4) * 16) ^ ((m & 7) << 4)));
            }
#pragma unroll
            for (int nf = 0; nf < 4; ++nf) {
                const int d = nf * 16 + (l & 15);
                bv8[nf] = *(const short8*)(VLDS(bs) + d * 128 + ((ks * 64 + (l >> 4) * 16) ^ ((d & 7) << 4)));
                float vs = 0.f;
#pragma unroll
                for (int e = 0; e < 8; ++e) vs += bf2f((u16)bv8[nf][e]);
                vsc[nf] += vs;
            }
#pragma unroll
            for (int mf = 0; mf < 4; ++mf)
#pragma unroll
                for (int nf = 0; nf < 4; ++nf)
                    acc[mf][nf] = __builtin_amdgcn_mfma_f32_16x16x32_bf16(am[mf], bv8[nf], acc[mf][nf], 0, 0, 0);
        }
    }
    if (l == 0) lstab[((size_t)ck * BHN + bh) * 4 + wv] = mrun;
    const size_t pbase = (size_t)ck * BHN + bh;
#pragma unroll
    for (int nf = 0; nf < 4; ++nf) {
        float v = ksc[nf];
        v += __shfl_xor(v, 16);
        v += __shfl_xor(v, 32);
        if (l < 16) ksum_part[pbase * MM + wv * 64 + nf * 16 + l] = v;
        float w = vsc[nf];
        w += __shfl_xor(w, 16);
        w += __shfl_xor(w, 32);
        if (wv == 0 && l < 16) vsum_part[pbase * HDD + nf * 16 + l] = w;
    }
#pragma unroll
    for (int mf = 0; mf < 4; ++mf)
#pragma unroll
        for (int nf = 0; nf < 4; ++nf)
            *(f32x4*)(kv_part + (pbase * HDD + nf * 16 + (l & 15)) * MM + wv * 64 + mf * 16 + (l >> 4) * 4) = acc[mf][nf];
    #undef KLDS
    #undef VLDS
    #undef KSTAGE
    #undef VSTAGE
}

// ---------------- reduceB3: rescale partials by exp(lstab - G), add eps terms ----------------
__global__ void reduceB3(const float* __restrict__ kv_part, const float* __restrict__ ksum_part,
                         const float* __restrict__ vsum_part, const float* __restrict__ lstab,
                         u16* __restrict__ Bmat) {
    __shared__ float f[8][4];
    const int bh = blockIdx.x, n = blockIdx.y, t = threadIdx.x;
    if (t < 32) {
        float lv = lstab[((size_t)(t >> 2) * BHN + bh) * 4 + (t & 3)];
        float g = lv;
#pragma unroll
        for (int o = 1; o < 32; o <<= 1) g = fmaxf(g, __shfl_xor(g, o));
        f[t >> 2][t & 3] = __expf(lv - g);
    }
    __syncthreads();
    const int grp = t >> 6;
    float s = 0.f;
    if (n < 64) {
        float vsg = 0.f;
#pragma unroll
        for (int ck = 0; ck < 8; ++ck) {
            vsg += vsum_part[((size_t)ck * BHN + bh) * HDD + n];
            s += kv_part[(((size_t)ck * BHN + bh) * HDD + n) * MM + t] * f[ck][grp];
        }
        s = 0.0625f * (s + 1e-4f * vsg);
    } else if (n == 64) {
#pragma unroll
        for (int ck = 0; ck < 8; ++ck)
            s += ksum_part[((size_t)ck * BHN + bh) * MM + t] * f[ck][grp];
        s = 0.0625f * (s + 1e-4f * 4096.0f);
    }
    Bmat[((size_t)bh * 80 + n) * MM + t] = (n <= 64) ? f2bf(s) : (u16)0;
}

// ---------------- out_fused v2: QBLK=64, B-frags direct from L2, no Blds ----------------
__global__ __launch_bounds__(256) void out_fused(
    const u16* __restrict__ Qh, const u16* __restrict__ projb,
    const float* __restrict__ dq, const u16* __restrict__ Bmat,
    float* __restrict__ out)
{
    __shared__ __align__(16) u16 Qlds[64 * 64];
    __shared__ __align__(16) u16 qlds[64 * 256];
    __shared__ float red[4][64];
    const int tid = threadIdx.x, l = tid & 63, wv = tid >> 6;
    const int rt = blockIdx.x, bh = blockIdx.y;
    const size_t srowbase = (size_t)bh * SS + rt * 64;
#pragma unroll
    for (int c = 0; c < 2; ++c) {
        const int rb = wv * 16 + c * 8;
        const int r = rb + (l >> 3);
        load_lds16(Qh + (srowbase + r) * HDD + (((l & 7) ^ (r & 7)) * 8), (char*)Qlds + rb * 128);
    }
    short8 pa[4][2];
#pragma unroll
    for (int mf = 0; mf < 4; ++mf)
#pragma unroll
        for (int ks = 0; ks < 2; ++ks)
            pa[mf][ks] = *(const short8*)(projb + (wv * 64 + mf * 16 + (l & 15)) * HDD + ks * 32 + (l >> 4) * 8);
    __syncthreads();
    f32x4 u[4][4] = {};
#pragma unroll
    for (int ks = 0; ks < 2; ++ks) {
        short8 bq8[4];
#pragma unroll
        for (int nf = 0; nf < 4; ++nf) {
            const int s = nf * 16 + (l & 15);
            bq8[nf] = *(const short8*)((const char*)Qlds + s * 128 + ((ks * 64 + (l >> 4) * 16) ^ ((s & 7) << 4)));
        }
#pragma unroll
        for (int mf = 0; mf < 4; ++mf)
#pragma unroll
            for (int nf = 0; nf < 4; ++nf)
                u[mf][nf] = __builtin_amdgcn_mfma_f32_16x16x32_bf16(pa[mf][ks], bq8[nf], u[mf][nf], 0, 0, 0);
    }
#pragma unroll
    for (int nf = 0; nf < 4; ++nf) {
        float v = -3.0e38f;
#pragma unroll
        for (int mf = 0; mf < 4; ++mf)
#pragma unroll
            for (int g = 0; g < 4; ++g) v = fmaxf(v, u[mf][nf][g]);
        v = fmaxf(v, __shfl_xor(v, 16));
        v = fmaxf(v, __shfl_xor(v, 32));
        if ((l >> 4) == 0) red[wv][nf * 16 + l] = v;
    }
    __syncthreads();
#pragma unroll
    for (int nf = 0; nf < 4; ++nf) {
        const int s = nf * 16 + (l & 15);
        const float mx = fmaxf(fmaxf(red[0][s], red[1][s]), fmaxf(red[2][s], red[3][s]));
        const float dg = dq[srowbase + s];
#pragma unroll
        for (int mf = 0; mf < 4; ++mf) {
            u16 h0 = f2bf(0.0625f * (__expf(u[mf][nf][0] - dg - mx) + 1e-4f));
            u16 h1 = f2bf(0.0625f * (__expf(u[mf][nf][1] - dg - mx) + 1e-4f));
            u16 h2 = f2bf(0.0625f * (__expf(u[mf][nf][2] - dg - mx) + 1e-4f));
            u16 h3 = f2bf(0.0625f * (__expf(u[mf][nf][3] - dg - mx) + 1e-4f));
            uint2 w; w.x = (u32)h0 | ((u32)h1 << 16); w.y = (u32)h2 | ((u32)h3 << 16);
            const int mb = (wv * 64 + mf * 16 + (l >> 4) * 4) * 2;
            *(uint2*)((char*)qlds + s * 512 + (mb ^ ((s & 7) << 4))) = w;
        }
    }
    __syncthreads();
    const u16* bbase = Bmat + (size_t)bh * 20480;
    f32x4 acc[4][2] = {};
#pragma unroll
    for (int kt = 0; kt < 8; ++kt) {
        short8 aq[4], bb[2];
#pragma unroll
        for (int mf = 0; mf < 4; ++mf) {
            const int s = mf * 16 + (l & 15);
            aq[mf] = *(const short8*)((const char*)qlds + s * 512 + ((kt * 64 + (l >> 4) * 16) ^ ((s & 7) << 4)));
        }
        bb[0] = *(const short8*)(bbase + (wv * 16 + (l & 15)) * 256 + kt * 32 + (l >> 4) * 8);
        bb[1] = *(const short8*)(bbase + (64 + (l & 15)) * 256 + kt * 32 + (l >> 4) * 8);
#pragma unroll
        for (int mf = 0; mf < 4; ++mf)
#pragma unroll
            for (int nf = 0; nf < 2; ++nf)
                acc[mf][nf] = __builtin_amdgcn_mfma_f32_16x16x32_bf16(aq[mf], bb[nf], acc[mf][nf], 0, 0, 0);
    }
    const int b = bh >> 4, h = bh & 15;
#pragma unroll
    for (int mf = 0; mf < 4; ++mf) {
#pragma unroll
        for (int g = 0; g < 4; ++g) {
            const float den = __shfl(acc[mf][1][g], (l & 48));
            const float z = 1.0f / (den + 1e-6f);
            const int s = rt * 64 + mf * 16 + (l >> 4) * 4 + g;
            out[((size_t)b * SS + s) * DD + h * HDD + wv * 16 + (l & 15)] = acc[mf][0][g] * z;
        }
    }
}

// ---------------- launcher ----------------
extern "C" void kernel_launch(void* const* d_in, const int* in_sizes, int n_in,
                              void* d_out, int out_size, void* d_ws, size_t ws_size,
                              hipStream_t stream)
{
    const float* X    = (const float*)d_in[0];
    const float* mask = (const float*)d_in[1];
    const float* Wq   = (const float*)d_in[2];
    const float* bq   = (const float*)d_in[3];
    const float* Wk   = (const float*)d_in[4];
    const float* bk   = (const float*)d_in[5];
    const float* Wv   = (const float*)d_in[6];
    const float* bv   = (const float*)d_in[7];
    const float* proj = (const float*)d_in[8];
    float* out = (float*)d_out;

    char* p = (char*)d_ws;
    u16* Xbf = (u16*)p;                            // 32 MB (aliased by kv_part after gemm1)
    float* kv_part = (float*)p; p += 33554432;
    u16* Wt = (u16*)p;    p += 6291456;
    u16* projb = (u16*)p; p += 32768;
    u16* Qh = (u16*)p;    p += 33554432;
    u16* Kh = (u16*)p;    p += 33554432;
    u16* Vt = (u16*)p;    p += 33554432;
    float* dq = (float*)p; p += 1048576;
    float* dk = (float*)p; p += 1048576;
    float* ksum_part = (float*)p; p += 524288;
    u16* Bmat = (u16*)p;  p += 2621440;
    float* vsum_part = (float*)p; p += 131072;     // [8][64][64] f32
    float* lstab = (float*)p; p += 8192;           // [8][64][4] f32
    if (ws_size < 145924096ull) return;

    hipFuncSetAttribute((const void*)gemm1_bk32, hipFuncAttributeMaxDynamicSharedMemorySize, 65536);
    hipFuncSetAttribute((const void*)kv_fused, hipFuncAttributeMaxDynamicSharedMemorySize, 81920);

    conv_bf16<<<16384, 256, 0, stream>>>(X, Xbf, 4194304);
    conv_w<<<dim3(48, 16), 256, 0, stream>>>(Wq, Wk, Wv, Wt);
    conv_bf16<<<16, 256, 0, stream>>>(proj, projb, 4096);
    gemm1_bk32<<<768, 512, 65536, stream>>>(Xbf, Wt, bq, bk, bv, mask, Qh, Kh, Vt, dq, dk);
    kv_fused<<<dim3(8, 64), 256, 81920, stream>>>(Kh, Vt, projb, dk, kv_part, ksum_part, vsum_part, lstab);
    reduceB3<<<dim3(64, 80), 256, 0, stream>>>(kv_part, ksum_part, vsum_part, lstab, Bmat);
    out_fused<<<dim3(64, 64), 256, 0, stream>>>(Qh, projb, dq, Bmat, out);
}

// Round 10
// 255.498 us; speedup vs baseline: 3.9705x; 3.9705x over previous
//
#include <hip/hip_runtime.h>
#include <stdint.h>

#define DEVI static __device__ __forceinline__

typedef unsigned short u16;
typedef unsigned int u32;
typedef __attribute__((ext_vector_type(8))) short short8;
typedef __attribute__((ext_vector_type(4))) float f32x4;
typedef __attribute__((ext_vector_type(4))) unsigned short ushort4_t;

#define BB 4
#define SS 4096
#define DD 1024
#define HH 16
#define HDD 64
#define MM 256
#define BHN 64

DEVI u16 f2bf(float f) {
    u32 u = __float_as_uint(f);
    u += 0x7fffu + ((u >> 16) & 1u);
    return (u16)(u >> 16);
}
DEVI float bf2f(u16 h) { return __uint_as_float(((u32)h) << 16); }

typedef __attribute__((address_space(1))) const unsigned int as1_u32;
typedef __attribute__((address_space(3))) unsigned int as3_u32;
DEVI void load_lds16(const void* g, void* lds) {
    __builtin_amdgcn_global_load_lds((as1_u32*)g, (as3_u32*)lds, 16, 0, 0);
}

// ---------------- conversion kernels ----------------

__global__ void conv_bf16(const float* __restrict__ src, u16* __restrict__ dst, int n4) {
    int i = blockIdx.x * 256 + threadIdx.x;
    if (i < n4) {
        float4 v = reinterpret_cast<const float4*>(src)[i];
        ushort4_t o = { f2bf(v.x), f2bf(v.y), f2bf(v.z), f2bf(v.w) };
        reinterpret_cast<ushort4_t*>(dst)[i] = o;
    }
}

__global__ void conv_w(const float* __restrict__ Wq, const float* __restrict__ Wk,
                       const float* __restrict__ Wv, u16* __restrict__ Wt) {
    __shared__ float tile[64][65];
    const int jt = blockIdx.x, kt = blockIdx.y;
    const float* src = (jt < 16) ? Wq : (jt < 32) ? Wk : Wv;
    const int j0 = (jt & 15) * 64, k0 = kt * 64;
    const int t = threadIdx.x;
    for (int i = 0; i < 16; ++i) {
        int lin = t + i * 256;
        int kl = lin >> 6, jl = lin & 63;
        tile[kl][jl] = src[(size_t)(k0 + kl) * DD + j0 + jl];
    }
    __syncthreads();
    const int jg0 = jt * 64;
    for (int i = 0; i < 16; ++i) {
        int lin = t + i * 256;
        int jl = lin >> 6, kl = lin & 63;
        Wt[(size_t)(jg0 + jl) * DD + k0 + kl] = f2bf(tile[kl][jl]);
    }
}

// ---------------- QKV GEMM: R4 structure (best measured: 115 µs) ----------------
// BM=BN=256, BK=64; 512 thr = 8 waves (2M x 4N); per-wave 128x64.
// LDS 2 x (32KB A + 32KB B) = 128KB double-buffered; drain vmcnt(0) at tile boundary.
// NOTE: per-wave 128x64 tile (acc[8][4]=128 regs) forbids >2 waves/EU launch bounds
// (R9: __launch_bounds__(512,4) capped VGPR -> acc spilled to scratch -> 8x slower).
__global__ __launch_bounds__(512, 2) void gemm1_big(
    const u16* __restrict__ Xbf, const u16* __restrict__ Wt,
    const float* __restrict__ bq, const float* __restrict__ bk, const float* __restrict__ bv,
    const float* __restrict__ mask,
    u16* __restrict__ Qh, u16* __restrict__ Kh, u16* __restrict__ Vt,
    float* __restrict__ dq, float* __restrict__ dk)
{
    extern __shared__ __align__(16) char smem[];
    const int tid = threadIdx.x, l = tid & 63, wv = tid >> 6;
    const int wm = wv >> 2, wn = wv & 3;
    const int bid = blockIdx.x;
    const int xcd = bid & 7, i6 = bid >> 3;          // 768 = 8 * 96, bijective
    const int bx = xcd * 8 + i6 / 12, by = i6 % 12;
    const int row0 = bx * 256, col0 = by * 256;

    const int srow = tid >> 3;
    const int scol = ((tid & 7) ^ (srow & 7)) * 8;

    #define ABUF(p) ((char*)smem + (p) * 32768)
    #define BBUF(p) ((char*)smem + 65536 + (p) * 32768)
    #define STA(p, kt, r) load_lds16(Xbf + (size_t)(row0 + (r)*64 + srow) * DD + (kt)*64 + scol, \
                                     ABUF(p) + (r)*8192 + wv*1024)
    #define STB(p, kt, r) load_lds16(Wt + (size_t)(col0 + (r)*64 + srow) * DD + (kt)*64 + scol, \
                                     BBUF(p) + (r)*8192 + wv*1024)

    STA(0,0,0); STA(0,0,1); STA(0,0,2); STA(0,0,3);
    STB(0,0,0); STB(0,0,1); STB(0,0,2); STB(0,0,3);
    asm volatile("s_waitcnt vmcnt(0)" ::: "memory");
    __builtin_amdgcn_s_barrier();
    __builtin_amdgcn_sched_barrier(0);

    f32x4 acc[8][4] = {};
    const int arow_b = wm * 128 + (l & 15);
    const int brow_b = wn * 64 + (l & 15);
    const int cb_b = (l >> 4) * 16;
    const int lx = (l & 7) << 4;

    for (int kt = 0; kt < 16; ++kt) {
        const int p = kt & 1, pn = p ^ 1;
        const bool more = (kt + 1) < 16;
        short8 bfr[4][2];
#pragma unroll
        for (int q = 0; q < 4; ++q) {
            if (more) {
                if (q == 0)      { STA(pn, kt + 1, 0); STA(pn, kt + 1, 1); }
                else if (q == 1) { STA(pn, kt + 1, 2); STA(pn, kt + 1, 3); }
                else if (q == 2) { STB(pn, kt + 1, 0); STB(pn, kt + 1, 1); }
                else             { STB(pn, kt + 1, 2); STB(pn, kt + 1, 3); }
            }
            if (q == 0) {
#pragma unroll
                for (int nf = 0; nf < 4; ++nf) {
                    const int br = brow_b + nf * 16;
#pragma unroll
                    for (int ks = 0; ks < 2; ++ks)
                        bfr[nf][ks] = *(const short8*)(BBUF(p) + br * 128 + ((cb_b + ks * 64) ^ lx));
                }
            }
            short8 a[2][2];
#pragma unroll
            for (int i = 0; i < 2; ++i) {
                const int ar = arow_b + (q * 2 + i) * 16;
#pragma unroll
                for (int ks = 0; ks < 2; ++ks)
                    a[i][ks] = *(const short8*)(ABUF(p) + ar * 128 + ((cb_b + ks * 64) ^ lx));
            }
            __builtin_amdgcn_s_setprio(1);
#pragma unroll
            for (int i = 0; i < 2; ++i)
#pragma unroll
                for (int nf = 0; nf < 4; ++nf) {
                    acc[q*2+i][nf] = __builtin_amdgcn_mfma_f32_16x16x32_bf16(a[i][0], bfr[nf][0], acc[q*2+i][nf], 0, 0, 0);
                    acc[q*2+i][nf] = __builtin_amdgcn_mfma_f32_16x16x32_bf16(a[i][1], bfr[nf][1], acc[q*2+i][nf], 0, 0, 0);
                }
            __builtin_amdgcn_s_setprio(0);
            __builtin_amdgcn_sched_barrier(0);
        }
        asm volatile("s_waitcnt vmcnt(0)" ::: "memory");
        __builtin_amdgcn_s_barrier();
        __builtin_amdgcn_sched_barrier(0);
    }

    // ---------- fused epilogue ----------
    const int region = by >> 2;
    const int h = ((by & 3) << 2) + wn;
    const int rg = row0 + wm * 128;
    const int b = rg >> 12;
    const int sb = rg & 4095;
    const size_t bh = (size_t)(b * HH + h);
    const int dd = l & 15;
    const int jbase = ((by & 3) << 8) + wn * 64;

    if (region == 0) {
        float bias[4];
#pragma unroll
        for (int nf = 0; nf < 4; ++nf) bias[nf] = bq[jbase + nf * 16 + dd];
#pragma unroll
        for (int mf = 0; mf < 8; ++mf) {
            float ds4[4];
#pragma unroll
            for (int g = 0; g < 4; ++g) {
                const int s = sb + mf * 16 + ((l >> 4) << 2) + g;
                float dsum = 0.f;
#pragma unroll
                for (int nf = 0; nf < 4; ++nf) {
                    u16 hv = f2bf((acc[mf][nf][g] + bias[nf]) * 0.125f);
                    Qh[(bh * SS + s) * HDD + nf * 16 + dd] = hv;
                    float fv = bf2f(hv);
                    dsum += fv * fv;
                }
                dsum += __shfl_xor(dsum, 1);
                dsum += __shfl_xor(dsum, 2);
                dsum += __shfl_xor(dsum, 4);
                dsum += __shfl_xor(dsum, 8);
                ds4[g] = 0.5f * dsum;
            }
            if (dd == 0)
                *(float4*)(dq + bh * SS + sb + mf * 16 + ((l >> 4) << 2)) =
                    make_float4(ds4[0], ds4[1], ds4[2], ds4[3]);
        }
    } else if (region == 1) {
        float bias[4];
#pragma unroll
        for (int nf = 0; nf < 4; ++nf) bias[nf] = bk[jbase + nf * 16 + dd];
#pragma unroll
        for (int mf = 0; mf < 8; ++mf) {
            float ds4[4];
#pragma unroll
            for (int g = 0; g < 4; ++g) {
                const int s = sb + mf * 16 + ((l >> 4) << 2) + g;
                const float m = mask[b * SS + s];
                float dsum = 0.f;
#pragma unroll
                for (int nf = 0; nf < 4; ++nf) {
                    u16 hv = f2bf((acc[mf][nf][g] + bias[nf]) * m * 0.125f);
                    Kh[(bh * SS + s) * HDD + nf * 16 + dd] = hv;
                    float fv = bf2f(hv);
                    dsum += fv * fv;
                }
                dsum += __shfl_xor(dsum, 1);
                dsum += __shfl_xor(dsum, 2);
                dsum += __shfl_xor(dsum, 4);
                dsum += __shfl_xor(dsum, 8);
                ds4[g] = 0.5f * dsum;
            }
            if (dd == 0)
                *(float4*)(dk + bh * SS + sb + mf * 16 + ((l >> 4) << 2)) =
                    make_float4(ds4[0], ds4[1], ds4[2], ds4[3]);
        }
    } else {
        float bias[4];
#pragma unroll
        for (int nf = 0; nf < 4; ++nf) bias[nf] = bv[jbase + nf * 16 + dd];
#pragma unroll
        for (int mf = 0; mf < 8; ++mf) {
            const int s0 = sb + mf * 16 + ((l >> 4) << 2);
#pragma unroll
            for (int nf = 0; nf < 4; ++nf) {
                ushort4_t pk;
#pragma unroll
                for (int g = 0; g < 4; ++g) {
                    const float m = mask[b * SS + s0 + g];
                    pk[g] = f2bf((acc[mf][nf][g] + bias[nf]) * m);
                }
                *(ushort4_t*)(Vt + (bh * HDD + nf * 16 + dd) * SS + s0) = pk;
            }
        }
    }
    #undef ABUF
    #undef BBUF
    #undef STA
    #undef STB
}

// ---------------- kv_fused v5: single-pass online-max (flash-style) ----------------
__global__ __launch_bounds__(256, 2) void kv_fused(
    const u16* __restrict__ Kh, const u16* __restrict__ Vt,
    const u16* __restrict__ projb, const float* __restrict__ dk,
    float* __restrict__ kv_part, float* __restrict__ ksum_part,
    float* __restrict__ vsum_part, float* __restrict__ lstab)
{
    extern __shared__ __align__(16) char ksm[];
    #define KLDS(b) ((char*)ksm + (b) * 8192)
    #define VLDS(b) ((char*)ksm + 24576 + (b) * 8192)
    u16* Kp = (u16*)((char*)ksm + 49152);
    const int tid = threadIdx.x, l = tid & 63, wv = tid >> 6;
    const int ck = blockIdx.x, bh = blockIdx.y;
    short8 pb[4][2];
#pragma unroll
    for (int nf = 0; nf < 4; ++nf)
#pragma unroll
        for (int ks = 0; ks < 2; ++ks)
            pb[nf][ks] = *(const short8*)(projb + (wv * 64 + nf * 16 + (l & 15)) * HDD + ks * 32 + (l >> 4) * 8);
    const size_t sbase = (size_t)bh * SS + ck * 512;

    #define KSTAGE(buf, it8) do { \
        const int s0_ = (it8) * 64; \
        _Pragma("unroll") \
        for (int c = 0; c < 2; ++c) { \
            const int rb = wv * 16 + c * 8; \
            const int r = rb + (l >> 3); \
            const int sc = ((l & 7) ^ (r & 7)) * 8; \
            load_lds16(Kh + (sbase + s0_ + r) * HDD + sc, KLDS(buf) + rb * 128); \
        } \
    } while (0)
    #define VSTAGE(buf, it8) do { \
        const int s0_ = (it8) * 64; \
        _Pragma("unroll") \
        for (int c = 0; c < 2; ++c) { \
            const int rb = wv * 16 + c * 8; \
            const int r = rb + (l >> 3); \
            const int sc = ((l & 7) ^ (r & 7)) * 8; \
            load_lds16(Vt + ((size_t)bh * HDD + r) * SS + ck * 512 + s0_ + sc, VLDS(buf) + rb * 128); \
        } \
    } while (0)

    float mrun = -3.0e38f;
    f32x4 acc[4][4] = {};
    float ksc[4] = {0.f, 0.f, 0.f, 0.f};
    float vsc[4] = {0.f, 0.f, 0.f, 0.f};
    KSTAGE(0, 0); VSTAGE(0, 0);
    for (int it = 0; it < 8; ++it) {
        if (it + 1 < 8) {
            KSTAGE((it + 1) % 3, it + 1);
            VSTAGE((it + 1) % 3, it + 1);
            asm volatile("s_waitcnt vmcnt(4)" ::: "memory");
        } else {
            asm volatile("s_waitcnt vmcnt(0)" ::: "memory");
        }
        __syncthreads();
        const int bs = it % 3;
        const int s0 = it * 64;
        f32x4 u4[4][4];
#pragma unroll
        for (int sf = 0; sf < 4; ++sf) {
#pragma unroll
            for (int nf = 0; nf < 4; ++nf) u4[sf][nf] = (f32x4){0.f, 0.f, 0.f, 0.f};
            const int s = sf * 16 + (l & 15);
#pragma unroll
            for (int ks = 0; ks < 2; ++ks) {
                short8 ak = *(const short8*)(KLDS(bs) + s * 128 + ((ks * 64 + (l >> 4) * 16) ^ ((s & 7) << 4)));
#pragma unroll
                for (int nf = 0; nf < 4; ++nf)
                    u4[sf][nf] = __builtin_amdgcn_mfma_f32_16x16x32_bf16(ak, pb[nf][ks], u4[sf][nf], 0, 0, 0);
            }
        }
        float pmax = -3.0e38f;
#pragma unroll
        for (int sf = 0; sf < 4; ++sf)
#pragma unroll
            for (int nf = 0; nf < 4; ++nf)
#pragma unroll
                for (int g = 0; g < 4; ++g) pmax = fmaxf(pmax, u4[sf][nf][g]);
#pragma unroll
        for (int o = 1; o < 64; o <<= 1) pmax = fmaxf(pmax, __shfl_xor(pmax, o));
        if (pmax > mrun) {                       // wave-uniform
            const float fac = __expf(mrun - pmax);
            mrun = pmax;
#pragma unroll
            for (int mf = 0; mf < 4; ++mf)
#pragma unroll
                for (int nf = 0; nf < 4; ++nf)
#pragma unroll
                    for (int g = 0; g < 4; ++g) acc[mf][nf][g] *= fac;
#pragma unroll
            for (int nf = 0; nf < 4; ++nf) ksc[nf] *= fac;
        }
#pragma unroll
        for (int sf = 0; sf < 4; ++sf) {
            const int srow = sf * 16 + (l >> 4) * 4;
            const float4 dkv = *(const float4*)(dk + sbase + s0 + srow);
#pragma unroll
            for (int nf = 0; nf < 4; ++nf) {
                const int m = wv * 64 + nf * 16 + (l & 15);
                u16 h0 = f2bf(__expf(u4[sf][nf][0] - dkv.x - mrun));
                u16 h1 = f2bf(__expf(u4[sf][nf][1] - dkv.y - mrun));
                u16 h2 = f2bf(__expf(u4[sf][nf][2] - dkv.z - mrun));
                u16 h3 = f2bf(__expf(u4[sf][nf][3] - dkv.w - mrun));
                ksc[nf] += bf2f(h0) + bf2f(h1) + bf2f(h2) + bf2f(h3);
                uint2 w; w.x = (u32)h0 | ((u32)h1 << 16); w.y = (u32)h2 | ((u32)h3 << 16);
                *(uint2*)((char*)Kp + m * 128 + ((srow * 2) ^ ((m & 7) << 4))) = w;
            }
        }
        __syncthreads();
#pragma unroll
        for (int ks = 0; ks < 2; ++ks) {
            short8 am[4], bv8[4];
#pragma unroll
            for (int mf = 0; mf < 4; ++mf) {
                const int m = wv * 64 + mf * 16 + (l & 15);
                am[mf] = *(const short8*)((const char*)Kp + m * 128 + ((ks * 64 + (l >> 4) * 16) ^ ((m & 7) << 4)));
            }
#pragma unroll
            for (int nf = 0; nf < 4; ++nf) {
                const int d = nf * 16 + (l & 15);
                bv8[nf] = *(const short8*)(VLDS(bs) + d * 128 + ((ks * 64 + (l >> 4) * 16) ^ ((d & 7) << 4)));
                float vs = 0.f;
#pragma unroll
                for (int e = 0; e < 8; ++e) vs += bf2f((u16)bv8[nf][e]);
                vsc[nf] += vs;
            }
#pragma unroll
            for (int mf = 0; mf < 4; ++mf)
#pragma unroll
                for (int nf = 0; nf < 4; ++nf)
                    acc[mf][nf] = __builtin_amdgcn_mfma_f32_16x16x32_bf16(am[mf], bv8[nf], acc[mf][nf], 0, 0, 0);
        }
    }
    if (l == 0) lstab[((size_t)ck * BHN + bh) * 4 + wv] = mrun;
    const size_t pbase = (size_t)ck * BHN + bh;
#pragma unroll
    for (int nf = 0; nf < 4; ++nf) {
        float v = ksc[nf];
        v += __shfl_xor(v, 16);
        v += __shfl_xor(v, 32);
        if (l < 16) ksum_part[pbase * MM + wv * 64 + nf * 16 + l] = v;
        float w = vsc[nf];
        w += __shfl_xor(w, 16);
        w += __shfl_xor(w, 32);
        if (wv == 0 && l < 16) vsum_part[pbase * HDD + nf * 16 + l] = w;
    }
#pragma unroll
    for (int mf = 0; mf < 4; ++mf)
#pragma unroll
        for (int nf = 0; nf < 4; ++nf)
            *(f32x4*)(kv_part + (pbase * HDD + nf * 16 + (l & 15)) * MM + wv * 64 + mf * 16 + (l >> 4) * 4) = acc[mf][nf];
    #undef KLDS
    #undef VLDS
    #undef KSTAGE
    #undef VSTAGE
}

// ---------------- reduceB3: rescale partials by exp(lstab - G), add eps terms ----------------
__global__ void reduceB3(const float* __restrict__ kv_part, const float* __restrict__ ksum_part,
                         const float* __restrict__ vsum_part, const float* __restrict__ lstab,
                         u16* __restrict__ Bmat) {
    __shared__ float f[8][4];
    const int bh = blockIdx.x, n = blockIdx.y, t = threadIdx.x;
    if (t < 32) {
        float lv = lstab[((size_t)(t >> 2) * BHN + bh) * 4 + (t & 3)];
        float g = lv;
#pragma unroll
        for (int o = 1; o < 32; o <<= 1) g = fmaxf(g, __shfl_xor(g, o));
        f[t >> 2][t & 3] = __expf(lv - g);
    }
    __syncthreads();
    const int grp = t >> 6;
    float s = 0.f;
    if (n < 64) {
        float vsg = 0.f;
#pragma unroll
        for (int ck = 0; ck < 8; ++ck) {
            vsg += vsum_part[((size_t)ck * BHN + bh) * HDD + n];
            s += kv_part[(((size_t)ck * BHN + bh) * HDD + n) * MM + t] * f[ck][grp];
        }
        s = 0.0625f * (s + 1e-4f * vsg);
    } else if (n == 64) {
#pragma unroll
        for (int ck = 0; ck < 8; ++ck)
            s += ksum_part[((size_t)ck * BHN + bh) * MM + t] * f[ck][grp];
        s = 0.0625f * (s + 1e-4f * 4096.0f);
    }
    Bmat[((size_t)bh * 80 + n) * MM + t] = (n <= 64) ? f2bf(s) : (u16)0;
}

// ---------------- out_fused v2: QBLK=64, B-frags direct from L2, no Blds ----------------
__global__ __launch_bounds__(256) void out_fused(
    const u16* __restrict__ Qh, const u16* __restrict__ projb,
    const float* __restrict__ dq, const u16* __restrict__ Bmat,
    float* __restrict__ out)
{
    __shared__ __align__(16) u16 Qlds[64 * 64];
    __shared__ __align__(16) u16 qlds[64 * 256];
    __shared__ float red[4][64];
    const int tid = threadIdx.x, l = tid & 63, wv = tid >> 6;
    const int rt = blockIdx.x, bh = blockIdx.y;
    const size_t srowbase = (size_t)bh * SS + rt * 64;
#pragma unroll
    for (int c = 0; c < 2; ++c) {
        const int rb = wv * 16 + c * 8;
        const int r = rb + (l >> 3);
        load_lds16(Qh + (srowbase + r) * HDD + (((l & 7) ^ (r & 7)) * 8), (char*)Qlds + rb * 128);
    }
    short8 pa[4][2];
#pragma unroll
    for (int mf = 0; mf < 4; ++mf)
#pragma unroll
        for (int ks = 0; ks < 2; ++ks)
            pa[mf][ks] = *(const short8*)(projb + (wv * 64 + mf * 16 + (l & 15)) * HDD + ks * 32 + (l >> 4) * 8);
    __syncthreads();
    f32x4 u[4][4] = {};
#pragma unroll
    for (int ks = 0; ks < 2; ++ks) {
        short8 bq8[4];
#pragma unroll
        for (int nf = 0; nf < 4; ++nf) {
            const int s = nf * 16 + (l & 15);
            bq8[nf] = *(const short8*)((const char*)Qlds + s * 128 + ((ks * 64 + (l >> 4) * 16) ^ ((s & 7) << 4)));
        }
#pragma unroll
        for (int mf = 0; mf < 4; ++mf)
#pragma unroll
            for (int nf = 0; nf < 4; ++nf)
                u[mf][nf] = __builtin_amdgcn_mfma_f32_16x16x32_bf16(pa[mf][ks], bq8[nf], u[mf][nf], 0, 0, 0);
    }
#pragma unroll
    for (int nf = 0; nf < 4; ++nf) {
        float v = -3.0e38f;
#pragma unroll
        for (int mf = 0; mf < 4; ++mf)
#pragma unroll
            for (int g = 0; g < 4; ++g) v = fmaxf(v, u[mf][nf][g]);
        v = fmaxf(v, __shfl_xor(v, 16));
        v = fmaxf(v, __shfl_xor(v, 32));
        if ((l >> 4) == 0) red[wv][nf * 16 + l] = v;
    }
    __syncthreads();
#pragma unroll
    for (int nf = 0; nf < 4; ++nf) {
        const int s = nf * 16 + (l & 15);
        const float mx = fmaxf(fmaxf(red[0][s], red[1][s]), fmaxf(red[2][s], red[3][s]));
        const float dg = dq[srowbase + s];
#pragma unroll
        for (int mf = 0; mf < 4; ++mf) {
            u16 h0 = f2bf(0.0625f * (__expf(u[mf][nf][0] - dg - mx) + 1e-4f));
            u16 h1 = f2bf(0.0625f * (__expf(u[mf][nf][1] - dg - mx) + 1e-4f));
            u16 h2 = f2bf(0.0625f * (__expf(u[mf][nf][2] - dg - mx) + 1e-4f));
            u16 h3 = f2bf(0.0625f * (__expf(u[mf][nf][3] - dg - mx) + 1e-4f));
            uint2 w; w.x = (u32)h0 | ((u32)h1 << 16); w.y = (u32)h2 | ((u32)h3 << 16);
            const int mb = (wv * 64 + mf * 16 + (l >> 4) * 4) * 2;
            *(uint2*)((char*)qlds + s * 512 + (mb ^ ((s & 7) << 4))) = w;
        }
    }
    __syncthreads();
    const u16* bbase = Bmat + (size_t)bh * 20480;
    f32x4 acc[4][2] = {};
#pragma unroll
    for (int kt = 0; kt < 8; ++kt) {
        short8 aq[4], bb[2];
#pragma unroll
        for (int mf = 0; mf < 4; ++mf) {
            const int s = mf * 16 + (l & 15);
            aq[mf] = *(const short8*)((const char*)qlds + s * 512 + ((kt * 64 + (l >> 4) * 16) ^ ((s & 7) << 4)));
        }
        bb[0] = *(const short8*)(bbase + (wv * 16 + (l & 15)) * 256 + kt * 32 + (l >> 4) * 8);
        bb[1] = *(const short8*)(bbase + (64 + (l & 15)) * 256 + kt * 32 + (l >> 4) * 8);
#pragma unroll
        for (int mf = 0; mf < 4; ++mf)
#pragma unroll
            for (int nf = 0; nf < 2; ++nf)
                acc[mf][nf] = __builtin_amdgcn_mfma_f32_16x16x32_bf16(aq[mf], bb[nf], acc[mf][nf], 0, 0, 0);
    }
    const int b = bh >> 4, h = bh & 15;
#pragma unroll
    for (int mf = 0; mf < 4; ++mf) {
#pragma unroll
        for (int g = 0; g < 4; ++g) {
            const float den = __shfl(acc[mf][1][g], (l & 48));
            const float z = 1.0f / (den + 1e-6f);
            const int s = rt * 64 + mf * 16 + (l >> 4) * 4 + g;
            out[((size_t)b * SS + s) * DD + h * HDD + wv * 16 + (l & 15)] = acc[mf][0][g] * z;
        }
    }
}

// ---------------- launcher ----------------
extern "C" void kernel_launch(void* const* d_in, const int* in_sizes, int n_in,
                              void* d_out, int out_size, void* d_ws, size_t ws_size,
                              hipStream_t stream)
{
    const float* X    = (const float*)d_in[0];
    const float* mask = (const float*)d_in[1];
    const float* Wq   = (const float*)d_in[2];
    const float* bq   = (const float*)d_in[3];
    const float* Wk   = (const float*)d_in[4];
    const float* bk   = (const float*)d_in[5];
    const float* Wv   = (const float*)d_in[6];
    const float* bv   = (const float*)d_in[7];
    const float* proj = (const float*)d_in[8];
    float* out = (float*)d_out;

    char* p = (char*)d_ws;
    u16* Xbf = (u16*)p;                            // 32 MB (aliased by kv_part after gemm1)
    float* kv_part = (float*)p; p += 33554432;
    u16* Wt = (u16*)p;    p += 6291456;
    u16* projb = (u16*)p; p += 32768;
    u16* Qh = (u16*)p;    p += 33554432;
    u16* Kh = (u16*)p;    p += 33554432;
    u16* Vt = (u16*)p;    p += 33554432;
    float* dq = (float*)p; p += 1048576;
    float* dk = (float*)p; p += 1048576;
    float* ksum_part = (float*)p; p += 524288;
    u16* Bmat = (u16*)p;  p += 2621440;
    float* vsum_part = (float*)p; p += 131072;     // [8][64][64] f32
    float* lstab = (float*)p; p += 8192;           // [8][64][4] f32
    if (ws_size < 145924096ull) return;

    hipFuncSetAttribute((const void*)gemm1_big, hipFuncAttributeMaxDynamicSharedMemorySize, 131072);
    hipFuncSetAttribute((const void*)kv_fused, hipFuncAttributeMaxDynamicSharedMemorySize, 81920);

    conv_bf16<<<16384, 256, 0, stream>>>(X, Xbf, 4194304);
    conv_w<<<dim3(48, 16), 256, 0, stream>>>(Wq, Wk, Wv, Wt);
    conv_bf16<<<16, 256, 0, stream>>>(proj, projb, 4096);
    gemm1_big<<<768, 512, 131072, stream>>>(Xbf, Wt, bq, bk, bv, mask, Qh, Kh, Vt, dq, dk);
    kv_fused<<<dim3(8, 64), 256, 81920, stream>>>(Kh, Vt, projb, dk, kv_part, ksum_part, vsum_part, lstab);
    reduceB3<<<dim3(64, 80), 256, 0, stream>>>(kv_part, ksum_part, vsum_part, lstab, Bmat);
    out_fused<<<dim3(64, 64), 256, 0, stream>>>(Qh, projb, dq, Bmat, out);
}

// Round 11
// 252.709 us; speedup vs baseline: 4.0143x; 1.0110x over previous
//
#include <hip/hip_runtime.h>
#include <stdint.h>

#define DEVI static __device__ __forceinline__

typedef unsigned short u16;
typedef unsigned int u32;
typedef __attribute__((ext_vector_type(8))) short short8;
typedef __attribute__((ext_vector_type(4))) float f32x4;
typedef __attribute__((ext_vector_type(4))) unsigned short ushort4_t;

#define BB 4
#define SS 4096
#define DD 1024
#define HH 16
#define HDD 64
#define MM 256
#define BHN 64

DEVI u16 f2bf(float f) {
    u32 u = __float_as_uint(f);
    u += 0x7fffu + ((u >> 16) & 1u);
    return (u16)(u >> 16);
}
DEVI float bf2f(u16 h) { return __uint_as_float(((u32)h) << 16); }

typedef __attribute__((address_space(1))) const unsigned int as1_u32;
typedef __attribute__((address_space(3))) unsigned int as3_u32;
DEVI void load_lds16(const void* g, void* lds) {
    __builtin_amdgcn_global_load_lds((as1_u32*)g, (as3_u32*)lds, 16, 0, 0);
}

// ---------------- conversion kernels ----------------

__global__ void conv_bf16(const float* __restrict__ src, u16* __restrict__ dst, int n4) {
    int i = blockIdx.x * 256 + threadIdx.x;
    if (i < n4) {
        float4 v = reinterpret_cast<const float4*>(src)[i];
        ushort4_t o = { f2bf(v.x), f2bf(v.y), f2bf(v.z), f2bf(v.w) };
        reinterpret_cast<ushort4_t*>(dst)[i] = o;
    }
}

__global__ void conv_w(const float* __restrict__ Wq, const float* __restrict__ Wk,
                       const float* __restrict__ Wv, u16* __restrict__ Wt) {
    __shared__ float tile[64][65];
    const int jt = blockIdx.x, kt = blockIdx.y;
    const float* src = (jt < 16) ? Wq : (jt < 32) ? Wk : Wv;
    const int j0 = (jt & 15) * 64, k0 = kt * 64;
    const int t = threadIdx.x;
    for (int i = 0; i < 16; ++i) {
        int lin = t + i * 256;
        int kl = lin >> 6, jl = lin & 63;
        tile[kl][jl] = src[(size_t)(k0 + kl) * DD + j0 + jl];
    }
    __syncthreads();
    const int jg0 = jt * 64;
    for (int i = 0; i < 16; ++i) {
        int lin = t + i * 256;
        int jl = lin >> 6, kl = lin & 63;
        Wt[(size_t)(jg0 + jl) * DD + k0 + kl] = f2bf(tile[kl][jl]);
    }
}

// ---------------- QKV GEMM: R4 structure (best measured: 115 µs) ----------------
// BM=BN=256, BK=64; 512 thr = 8 waves (2M x 4N); per-wave 128x64.
// LDS 2 x (32KB A + 32KB B) = 128KB double-buffered; drain vmcnt(0) at tile boundary.
// NOTE: per-wave 128x64 tile (acc[8][4]=128 regs) forbids >2 waves/EU launch bounds
// (R9: __launch_bounds__(512,4) capped VGPR -> acc spilled to scratch -> 8x slower).
__global__ __launch_bounds__(512, 2) void gemm1_big(
    const u16* __restrict__ Xbf, const u16* __restrict__ Wt,
    const float* __restrict__ bq, const float* __restrict__ bk, const float* __restrict__ bv,
    const float* __restrict__ mask,
    u16* __restrict__ Qh, u16* __restrict__ Kh, u16* __restrict__ Vt,
    float* __restrict__ dq, float* __restrict__ dk)
{
    extern __shared__ __align__(16) char smem[];
    const int tid = threadIdx.x, l = tid & 63, wv = tid >> 6;
    const int wm = wv >> 2, wn = wv & 3;
    const int bid = blockIdx.x;
    const int xcd = bid & 7, i6 = bid >> 3;          // 768 = 8 * 96, bijective
    const int bx = xcd * 8 + i6 / 12, by = i6 % 12;
    const int row0 = bx * 256, col0 = by * 256;

    const int srow = tid >> 3;
    const int scol = ((tid & 7) ^ (srow & 7)) * 8;

    #define ABUF(p) ((char*)smem + (p) * 32768)
    #define BBUF(p) ((char*)smem + 65536 + (p) * 32768)
    #define STA(p, kt, r) load_lds16(Xbf + (size_t)(row0 + (r)*64 + srow) * DD + (kt)*64 + scol, \
                                     ABUF(p) + (r)*8192 + wv*1024)
    #define STB(p, kt, r) load_lds16(Wt + (size_t)(col0 + (r)*64 + srow) * DD + (kt)*64 + scol, \
                                     BBUF(p) + (r)*8192 + wv*1024)

    STA(0,0,0); STA(0,0,1); STA(0,0,2); STA(0,0,3);
    STB(0,0,0); STB(0,0,1); STB(0,0,2); STB(0,0,3);
    asm volatile("s_waitcnt vmcnt(0)" ::: "memory");
    __builtin_amdgcn_s_barrier();
    __builtin_amdgcn_sched_barrier(0);

    f32x4 acc[8][4] = {};
    const int arow_b = wm * 128 + (l & 15);
    const int brow_b = wn * 64 + (l & 15);
    const int cb_b = (l >> 4) * 16;
    const int lx = (l & 7) << 4;

    for (int kt = 0; kt < 16; ++kt) {
        const int p = kt & 1, pn = p ^ 1;
        const bool more = (kt + 1) < 16;
        short8 bfr[4][2];
#pragma unroll
        for (int q = 0; q < 4; ++q) {
            if (more) {
                if (q == 0)      { STA(pn, kt + 1, 0); STA(pn, kt + 1, 1); }
                else if (q == 1) { STA(pn, kt + 1, 2); STA(pn, kt + 1, 3); }
                else if (q == 2) { STB(pn, kt + 1, 0); STB(pn, kt + 1, 1); }
                else             { STB(pn, kt + 1, 2); STB(pn, kt + 1, 3); }
            }
            if (q == 0) {
#pragma unroll
                for (int nf = 0; nf < 4; ++nf) {
                    const int br = brow_b + nf * 16;
#pragma unroll
                    for (int ks = 0; ks < 2; ++ks)
                        bfr[nf][ks] = *(const short8*)(BBUF(p) + br * 128 + ((cb_b + ks * 64) ^ lx));
                }
            }
            short8 a[2][2];
#pragma unroll
            for (int i = 0; i < 2; ++i) {
                const int ar = arow_b + (q * 2 + i) * 16;
#pragma unroll
                for (int ks = 0; ks < 2; ++ks)
                    a[i][ks] = *(const short8*)(ABUF(p) + ar * 128 + ((cb_b + ks * 64) ^ lx));
            }
            __builtin_amdgcn_s_setprio(1);
#pragma unroll
            for (int i = 0; i < 2; ++i)
#pragma unroll
                for (int nf = 0; nf < 4; ++nf) {
                    acc[q*2+i][nf] = __builtin_amdgcn_mfma_f32_16x16x32_bf16(a[i][0], bfr[nf][0], acc[q*2+i][nf], 0, 0, 0);
                    acc[q*2+i][nf] = __builtin_amdgcn_mfma_f32_16x16x32_bf16(a[i][1], bfr[nf][1], acc[q*2+i][nf], 0, 0, 0);
                }
            __builtin_amdgcn_s_setprio(0);
            __builtin_amdgcn_sched_barrier(0);
        }
        asm volatile("s_waitcnt vmcnt(0)" ::: "memory");
        __builtin_amdgcn_s_barrier();
        __builtin_amdgcn_sched_barrier(0);
    }

    // ---------- fused epilogue ----------
    const int region = by >> 2;
    const int h = ((by & 3) << 2) + wn;
    const int rg = row0 + wm * 128;
    const int b = rg >> 12;
    const int sb = rg & 4095;
    const size_t bh = (size_t)(b * HH + h);
    const int dd = l & 15;
    const int jbase = ((by & 3) << 8) + wn * 64;

    if (region == 0) {
        float bias[4];
#pragma unroll
        for (int nf = 0; nf < 4; ++nf) bias[nf] = bq[jbase + nf * 16 + dd];
#pragma unroll
        for (int mf = 0; mf < 8; ++mf) {
            float ds4[4];
#pragma unroll
            for (int g = 0; g < 4; ++g) {
                const int s = sb + mf * 16 + ((l >> 4) << 2) + g;
                float dsum = 0.f;
#pragma unroll
                for (int nf = 0; nf < 4; ++nf) {
                    u16 hv = f2bf((acc[mf][nf][g] + bias[nf]) * 0.125f);
                    Qh[(bh * SS + s) * HDD + nf * 16 + dd] = hv;
                    float fv = bf2f(hv);
                    dsum += fv * fv;
                }
                dsum += __shfl_xor(dsum, 1);
                dsum += __shfl_xor(dsum, 2);
                dsum += __shfl_xor(dsum, 4);
                dsum += __shfl_xor(dsum, 8);
                ds4[g] = 0.5f * dsum;
            }
            if (dd == 0)
                *(float4*)(dq + bh * SS + sb + mf * 16 + ((l >> 4) << 2)) =
                    make_float4(ds4[0], ds4[1], ds4[2], ds4[3]);
        }
    } else if (region == 1) {
        float bias[4];
#pragma unroll
        for (int nf = 0; nf < 4; ++nf) bias[nf] = bk[jbase + nf * 16 + dd];
#pragma unroll
        for (int mf = 0; mf < 8; ++mf) {
            float ds4[4];
#pragma unroll
            for (int g = 0; g < 4; ++g) {
                const int s = sb + mf * 16 + ((l >> 4) << 2) + g;
                const float m = mask[b * SS + s];
                float dsum = 0.f;
#pragma unroll
                for (int nf = 0; nf < 4; ++nf) {
                    u16 hv = f2bf((acc[mf][nf][g] + bias[nf]) * m * 0.125f);
                    Kh[(bh * SS + s) * HDD + nf * 16 + dd] = hv;
                    float fv = bf2f(hv);
                    dsum += fv * fv;
                }
                dsum += __shfl_xor(dsum, 1);
                dsum += __shfl_xor(dsum, 2);
                dsum += __shfl_xor(dsum, 4);
                dsum += __shfl_xor(dsum, 8);
                ds4[g] = 0.5f * dsum;
            }
            if (dd == 0)
                *(float4*)(dk + bh * SS + sb + mf * 16 + ((l >> 4) << 2)) =
                    make_float4(ds4[0], ds4[1], ds4[2], ds4[3]);
        }
    } else {
        float bias[4];
#pragma unroll
        for (int nf = 0; nf < 4; ++nf) bias[nf] = bv[jbase + nf * 16 + dd];
#pragma unroll
        for (int mf = 0; mf < 8; ++mf) {
            const int s0 = sb + mf * 16 + ((l >> 4) << 2);
#pragma unroll
            for (int nf = 0; nf < 4; ++nf) {
                ushort4_t pk;
#pragma unroll
                for (int g = 0; g < 4; ++g) {
                    const float m = mask[b * SS + s0 + g];
                    pk[g] = f2bf((acc[mf][nf][g] + bias[nf]) * m);
                }
                *(ushort4_t*)(Vt + (bh * HDD + nf * 16 + dd) * SS + s0) = pk;
            }
        }
    }
    #undef ABUF
    #undef BBUF
    #undef STA
    #undef STB
}

// ---------------- kv_fused v6: online-max + defer-max(8) + wv0-only vsum ----------------
__global__ __launch_bounds__(256, 2) void kv_fused(
    const u16* __restrict__ Kh, const u16* __restrict__ Vt,
    const u16* __restrict__ projb, const float* __restrict__ dk,
    float* __restrict__ kv_part, float* __restrict__ ksum_part,
    float* __restrict__ vsum_part, float* __restrict__ lstab)
{
    extern __shared__ __align__(16) char ksm[];
    #define KLDS(b) ((char*)ksm + (b) * 8192)
    #define VLDS(b) ((char*)ksm + 24576 + (b) * 8192)
    u16* Kp = (u16*)((char*)ksm + 49152);
    const int tid = threadIdx.x, l = tid & 63, wv = tid >> 6;
    const int ck = blockIdx.x, bh = blockIdx.y;
    short8 pb[4][2];
#pragma unroll
    for (int nf = 0; nf < 4; ++nf)
#pragma unroll
        for (int ks = 0; ks < 2; ++ks)
            pb[nf][ks] = *(const short8*)(projb + (wv * 64 + nf * 16 + (l & 15)) * HDD + ks * 32 + (l >> 4) * 8);
    const size_t sbase = (size_t)bh * SS + ck * 512;

    #define KSTAGE(buf, it8) do { \
        const int s0_ = (it8) * 64; \
        _Pragma("unroll") \
        for (int c = 0; c < 2; ++c) { \
            const int rb = wv * 16 + c * 8; \
            const int r = rb + (l >> 3); \
            const int sc = ((l & 7) ^ (r & 7)) * 8; \
            load_lds16(Kh + (sbase + s0_ + r) * HDD + sc, KLDS(buf) + rb * 128); \
        } \
    } while (0)
    #define VSTAGE(buf, it8) do { \
        const int s0_ = (it8) * 64; \
        _Pragma("unroll") \
        for (int c = 0; c < 2; ++c) { \
            const int rb = wv * 16 + c * 8; \
            const int r = rb + (l >> 3); \
            const int sc = ((l & 7) ^ (r & 7)) * 8; \
            load_lds16(Vt + ((size_t)bh * HDD + r) * SS + ck * 512 + s0_ + sc, VLDS(buf) + rb * 128); \
        } \
    } while (0)

    float mrun = -3.0e38f;
    f32x4 acc[4][4] = {};
    float ksc[4] = {0.f, 0.f, 0.f, 0.f};
    float vsc[4] = {0.f, 0.f, 0.f, 0.f};
    KSTAGE(0, 0); VSTAGE(0, 0);
    for (int it = 0; it < 8; ++it) {
        if (it + 1 < 8) {
            KSTAGE((it + 1) % 3, it + 1);
            VSTAGE((it + 1) % 3, it + 1);
            asm volatile("s_waitcnt vmcnt(4)" ::: "memory");
        } else {
            asm volatile("s_waitcnt vmcnt(0)" ::: "memory");
        }
        __syncthreads();
        const int bs = it % 3;
        const int s0 = it * 64;
        f32x4 u4[4][4];
#pragma unroll
        for (int sf = 0; sf < 4; ++sf) {
#pragma unroll
            for (int nf = 0; nf < 4; ++nf) u4[sf][nf] = (f32x4){0.f, 0.f, 0.f, 0.f};
            const int s = sf * 16 + (l & 15);
#pragma unroll
            for (int ks = 0; ks < 2; ++ks) {
                short8 ak = *(const short8*)(KLDS(bs) + s * 128 + ((ks * 64 + (l >> 4) * 16) ^ ((s & 7) << 4)));
#pragma unroll
                for (int nf = 0; nf < 4; ++nf)
                    u4[sf][nf] = __builtin_amdgcn_mfma_f32_16x16x32_bf16(ak, pb[nf][ks], u4[sf][nf], 0, 0, 0);
            }
        }
        float pmax = -3.0e38f;
#pragma unroll
        for (int sf = 0; sf < 4; ++sf)
#pragma unroll
            for (int nf = 0; nf < 4; ++nf)
#pragma unroll
                for (int g = 0; g < 4; ++g) pmax = fmaxf(pmax, u4[sf][nf][g]);
#pragma unroll
        for (int o = 1; o < 64; o <<= 1) pmax = fmaxf(pmax, __shfl_xor(pmax, o));
        // defer-max (T13): rescale only when the max grows by >8; p stays <= e^8
        if (pmax > mrun + 8.0f) {                // wave-uniform
            const float fac = __expf(mrun - pmax);
            mrun = pmax;
#pragma unroll
            for (int mf = 0; mf < 4; ++mf)
#pragma unroll
                for (int nf = 0; nf < 4; ++nf)
#pragma unroll
                    for (int g = 0; g < 4; ++g) acc[mf][nf][g] *= fac;
#pragma unroll
            for (int nf = 0; nf < 4; ++nf) ksc[nf] *= fac;
        }
#pragma unroll
        for (int sf = 0; sf < 4; ++sf) {
            const int srow = sf * 16 + (l >> 4) * 4;
            const float4 dkv = *(const float4*)(dk + sbase + s0 + srow);
            // hoist per-g bias (dkv + mrun)
            const float b0 = dkv.x + mrun, b1 = dkv.y + mrun, b2 = dkv.z + mrun, b3 = dkv.w + mrun;
#pragma unroll
            for (int nf = 0; nf < 4; ++nf) {
                const int m = wv * 64 + nf * 16 + (l & 15);
                float p0 = __expf(u4[sf][nf][0] - b0);
                float p1 = __expf(u4[sf][nf][1] - b1);
                float p2 = __expf(u4[sf][nf][2] - b2);
                float p3 = __expf(u4[sf][nf][3] - b3);
                ksc[nf] += (p0 + p1) + (p2 + p3);   // unrounded: closer to exact ref
                u16 h0 = f2bf(p0), h1 = f2bf(p1), h2 = f2bf(p2), h3 = f2bf(p3);
                uint2 w; w.x = (u32)h0 | ((u32)h1 << 16); w.y = (u32)h2 | ((u32)h3 << 16);
                *(uint2*)((char*)Kp + m * 128 + ((srow * 2) ^ ((m & 7) << 4))) = w;
            }
        }
        __syncthreads();
#pragma unroll
        for (int ks = 0; ks < 2; ++ks) {
            short8 am[4], bv8[4];
#pragma unroll
            for (int mf = 0; mf < 4; ++mf) {
                const int m = wv * 64 + mf * 16 + (l & 15);
                am[mf] = *(const short8*)((const char*)Kp + m * 128 + ((ks * 64 + (l >> 4) * 16) ^ ((m & 7) << 4)));
            }
#pragma unroll
            for (int nf = 0; nf < 4; ++nf) {
                const int d = nf * 16 + (l & 15);
                bv8[nf] = *(const short8*)(VLDS(bs) + d * 128 + ((ks * 64 + (l >> 4) * 16) ^ ((d & 7) << 4)));
            }
            if (wv == 0) {                         // vsum identical across waves: compute once
#pragma unroll
                for (int nf = 0; nf < 4; ++nf) {
                    float vs = 0.f;
#pragma unroll
                    for (int e = 0; e < 8; ++e) vs += bf2f((u16)bv8[nf][e]);
                    vsc[nf] += vs;
                }
            }
#pragma unroll
            for (int mf = 0; mf < 4; ++mf)
#pragma unroll
                for (int nf = 0; nf < 4; ++nf)
                    acc[mf][nf] = __builtin_amdgcn_mfma_f32_16x16x32_bf16(am[mf], bv8[nf], acc[mf][nf], 0, 0, 0);
        }
    }
    if (l == 0) lstab[((size_t)ck * BHN + bh) * 4 + wv] = mrun;
    const size_t pbase = (size_t)ck * BHN + bh;
#pragma unroll
    for (int nf = 0; nf < 4; ++nf) {
        float v = ksc[nf];
        v += __shfl_xor(v, 16);
        v += __shfl_xor(v, 32);
        if (l < 16) ksum_part[pbase * MM + wv * 64 + nf * 16 + l] = v;
        if (wv == 0) {
            float w = vsc[nf];
            w += __shfl_xor(w, 16);
            w += __shfl_xor(w, 32);
            if (l < 16) vsum_part[pbase * HDD + nf * 16 + l] = w;
        }
    }
#pragma unroll
    for (int mf = 0; mf < 4; ++mf)
#pragma unroll
        for (int nf = 0; nf < 4; ++nf)
            *(f32x4*)(kv_part + (pbase * HDD + nf * 16 + (l & 15)) * MM + wv * 64 + mf * 16 + (l >> 4) * 4) = acc[mf][nf];
    #undef KLDS
    #undef VLDS
    #undef KSTAGE
    #undef VSTAGE
}

// ---------------- reduceB3: rescale partials by exp(lstab - G), add eps terms ----------------
__global__ void reduceB3(const float* __restrict__ kv_part, const float* __restrict__ ksum_part,
                         const float* __restrict__ vsum_part, const float* __restrict__ lstab,
                         u16* __restrict__ Bmat) {
    __shared__ float f[8][4];
    const int bh = blockIdx.x, n = blockIdx.y, t = threadIdx.x;
    if (t < 32) {
        float lv = lstab[((size_t)(t >> 2) * BHN + bh) * 4 + (t & 3)];
        float g = lv;
#pragma unroll
        for (int o = 1; o < 32; o <<= 1) g = fmaxf(g, __shfl_xor(g, o));
        f[t >> 2][t & 3] = __expf(lv - g);
    }
    __syncthreads();
    const int grp = t >> 6;
    float s = 0.f;
    if (n < 64) {
        float vsg = 0.f;
#pragma unroll
        for (int ck = 0; ck < 8; ++ck) {
            vsg += vsum_part[((size_t)ck * BHN + bh) * HDD + n];
            s += kv_part[(((size_t)ck * BHN + bh) * HDD + n) * MM + t] * f[ck][grp];
        }
        s = 0.0625f * (s + 1e-4f * vsg);
    } else if (n == 64) {
#pragma unroll
        for (int ck = 0; ck < 8; ++ck)
            s += ksum_part[((size_t)ck * BHN + bh) * MM + t] * f[ck][grp];
        s = 0.0625f * (s + 1e-4f * 4096.0f);
    }
    Bmat[((size_t)bh * 80 + n) * MM + t] = (n <= 64) ? f2bf(s) : (u16)0;
}

// ---------------- out_fused v2: QBLK=64, B-frags direct from L2, no Blds ----------------
__global__ __launch_bounds__(256) void out_fused(
    const u16* __restrict__ Qh, const u16* __restrict__ projb,
    const float* __restrict__ dq, const u16* __restrict__ Bmat,
    float* __restrict__ out)
{
    __shared__ __align__(16) u16 Qlds[64 * 64];
    __shared__ __align__(16) u16 qlds[64 * 256];
    __shared__ float red[4][64];
    const int tid = threadIdx.x, l = tid & 63, wv = tid >> 6;
    const int rt = blockIdx.x, bh = blockIdx.y;
    const size_t srowbase = (size_t)bh * SS + rt * 64;
#pragma unroll
    for (int c = 0; c < 2; ++c) {
        const int rb = wv * 16 + c * 8;
        const int r = rb + (l >> 3);
        load_lds16(Qh + (srowbase + r) * HDD + (((l & 7) ^ (r & 7)) * 8), (char*)Qlds + rb * 128);
    }
    short8 pa[4][2];
#pragma unroll
    for (int mf = 0; mf < 4; ++mf)
#pragma unroll
        for (int ks = 0; ks < 2; ++ks)
            pa[mf][ks] = *(const short8*)(projb + (wv * 64 + mf * 16 + (l & 15)) * HDD + ks * 32 + (l >> 4) * 8);
    __syncthreads();
    f32x4 u[4][4] = {};
#pragma unroll
    for (int ks = 0; ks < 2; ++ks) {
        short8 bq8[4];
#pragma unroll
        for (int nf = 0; nf < 4; ++nf) {
            const int s = nf * 16 + (l & 15);
            bq8[nf] = *(const short8*)((const char*)Qlds + s * 128 + ((ks * 64 + (l >> 4) * 16) ^ ((s & 7) << 4)));
        }
#pragma unroll
        for (int mf = 0; mf < 4; ++mf)
#pragma unroll
            for (int nf = 0; nf < 4; ++nf)
                u[mf][nf] = __builtin_amdgcn_mfma_f32_16x16x32_bf16(pa[mf][ks], bq8[nf], u[mf][nf], 0, 0, 0);
    }
#pragma unroll
    for (int nf = 0; nf < 4; ++nf) {
        float v = -3.0e38f;
#pragma unroll
        for (int mf = 0; mf < 4; ++mf)
#pragma unroll
            for (int g = 0; g < 4; ++g) v = fmaxf(v, u[mf][nf][g]);
        v = fmaxf(v, __shfl_xor(v, 16));
        v = fmaxf(v, __shfl_xor(v, 32));
        if ((l >> 4) == 0) red[wv][nf * 16 + l] = v;
    }
    __syncthreads();
#pragma unroll
    for (int nf = 0; nf < 4; ++nf) {
        const int s = nf * 16 + (l & 15);
        const float mx = fmaxf(fmaxf(red[0][s], red[1][s]), fmaxf(red[2][s], red[3][s]));
        const float dgmx = dq[srowbase + s] + mx;    // hoisted per-s bias
#pragma unroll
        for (int mf = 0; mf < 4; ++mf) {
            u16 h0 = f2bf(0.0625f * (__expf(u[mf][nf][0] - dgmx) + 1e-4f));
            u16 h1 = f2bf(0.0625f * (__expf(u[mf][nf][1] - dgmx) + 1e-4f));
            u16 h2 = f2bf(0.0625f * (__expf(u[mf][nf][2] - dgmx) + 1e-4f));
            u16 h3 = f2bf(0.0625f * (__expf(u[mf][nf][3] - dgmx) + 1e-4f));
            uint2 w; w.x = (u32)h0 | ((u32)h1 << 16); w.y = (u32)h2 | ((u32)h3 << 16);
            const int mb = (wv * 64 + mf * 16 + (l >> 4) * 4) * 2;
            *(uint2*)((char*)qlds + s * 512 + (mb ^ ((s & 7) << 4))) = w;
        }
    }
    __syncthreads();
    const u16* bbase = Bmat + (size_t)bh * 20480;
    f32x4 acc[4][2] = {};
#pragma unroll
    for (int kt = 0; kt < 8; ++kt) {
        short8 aq[4], bb[2];
#pragma unroll
        for (int mf = 0; mf < 4; ++mf) {
            const int s = mf * 16 + (l & 15);
            aq[mf] = *(const short8*)((const char*)qlds + s * 512 + ((kt * 64 + (l >> 4) * 16) ^ ((s & 7) << 4)));
        }
        bb[0] = *(const short8*)(bbase + (wv * 16 + (l & 15)) * 256 + kt * 32 + (l >> 4) * 8);
        bb[1] = *(const short8*)(bbase + (64 + (l & 15)) * 256 + kt * 32 + (l >> 4) * 8);
#pragma unroll
        for (int mf = 0; mf < 4; ++mf)
#pragma unroll
            for (int nf = 0; nf < 2; ++nf)
                acc[mf][nf] = __builtin_amdgcn_mfma_f32_16x16x32_bf16(aq[mf], bb[nf], acc[mf][nf], 0, 0, 0);
    }
    const int b = bh >> 4, h = bh & 15;
#pragma unroll
    for (int mf = 0; mf < 4; ++mf) {
#pragma unroll
        for (int g = 0; g < 4; ++g) {
            const float den = __shfl(acc[mf][1][g], (l & 48));
            const float z = 1.0f / (den + 1e-6f);
            const int s = rt * 64 + mf * 16 + (l >> 4) * 4 + g;
            out[((size_t)b * SS + s) * DD + h * HDD + wv * 16 + (l & 15)] = acc[mf][0][g] * z;
        }
    }
}

// ---------------- launcher ----------------
extern "C" void kernel_launch(void* const* d_in, const int* in_sizes, int n_in,
                              void* d_out, int out_size, void* d_ws, size_t ws_size,
                              hipStream_t stream)
{
    const float* X    = (const float*)d_in[0];
    const float* mask = (const float*)d_in[1];
    const float* Wq   = (const float*)d_in[2];
    const float* bq   = (const float*)d_in[3];
    const float* Wk   = (const float*)d_in[4];
    const float* bk   = (const float*)d_in[5];
    const float* Wv   = (const float*)d_in[6];
    const float* bv   = (const float*)d_in[7];
    const float* proj = (const float*)d_in[8];
    float* out = (float*)d_out;

    char* p = (char*)d_ws;
    u16* Xbf = (u16*)p;                            // 32 MB (aliased by kv_part after gemm1)
    float* kv_part = (float*)p; p += 33554432;
    u16* Wt = (u16*)p;    p += 6291456;
    u16* projb = (u16*)p; p += 32768;
    u16* Qh = (u16*)p;    p += 33554432;
    u16* Kh = (u16*)p;    p += 33554432;
    u16* Vt = (u16*)p;    p += 33554432;
    float* dq = (float*)p; p += 1048576;
    float* dk = (float*)p; p += 1048576;
    float* ksum_part = (float*)p; p += 524288;
    u16* Bmat = (u16*)p;  p += 2621440;
    float* vsum_part = (float*)p; p += 131072;     // [8][64][64] f32
    float* lstab = (float*)p; p += 8192;           // [8][64][4] f32
    if (ws_size < 145924096ull) return;

    hipFuncSetAttribute((const void*)gemm1_big, hipFuncAttributeMaxDynamicSharedMemorySize, 131072);
    hipFuncSetAttribute((const void*)kv_fused, hipFuncAttributeMaxDynamicSharedMemorySize, 81920);

    conv_bf16<<<16384, 256, 0, stream>>>(X, Xbf, 4194304);
    conv_w<<<dim3(48, 16), 256, 0, stream>>>(Wq, Wk, Wv, Wt);
    conv_bf16<<<16, 256, 0, stream>>>(proj, projb, 4096);
    gemm1_big<<<768, 512, 131072, stream>>>(Xbf, Wt, bq, bk, bv, mask, Qh, Kh, Vt, dq, dk);
    kv_fused<<<dim3(8, 64), 256, 81920, stream>>>(Kh, Vt, projb, dk, kv_part, ksum_part, vsum_part, lstab);
    reduceB3<<<dim3(64, 80), 256, 0, stream>>>(kv_part, ksum_part, vsum_part, lstab, Bmat);
    out_fused<<<dim3(64, 64), 256, 0, stream>>>(Qh, projb, dq, Bmat, out);
}

// Round 12
// 250.152 us; speedup vs baseline: 4.0553x; 1.0102x over previous
//
#include <hip/hip_runtime.h>
#include <stdint.h>

#define DEVI static __device__ __forceinline__

typedef unsigned short u16;
typedef unsigned int u32;
typedef __attribute__((ext_vector_type(8))) short short8;
typedef __attribute__((ext_vector_type(4))) float f32x4;
typedef __attribute__((ext_vector_type(4))) unsigned short ushort4_t;

#define BB 4
#define SS 4096
#define DD 1024
#define HH 16
#define HDD 64
#define MM 256
#define BHN 64

DEVI u16 f2bf(float f) {
    u32 u = __float_as_uint(f);
    u += 0x7fffu + ((u >> 16) & 1u);
    return (u16)(u >> 16);
}
DEVI float bf2f(u16 h) { return __uint_as_float(((u32)h) << 16); }

typedef __attribute__((address_space(1))) const unsigned int as1_u32;
typedef __attribute__((address_space(3))) unsigned int as3_u32;
DEVI void load_lds16(const void* g, void* lds) {
    __builtin_amdgcn_global_load_lds((as1_u32*)g, (as3_u32*)lds, 16, 0, 0);
}

// ---------------- conversion kernels ----------------

__global__ void conv_bf16(const float* __restrict__ src, u16* __restrict__ dst, int n4) {
    int i = blockIdx.x * 256 + threadIdx.x;
    if (i < n4) {
        float4 v = reinterpret_cast<const float4*>(src)[i];
        ushort4_t o = { f2bf(v.x), f2bf(v.y), f2bf(v.z), f2bf(v.w) };
        reinterpret_cast<ushort4_t*>(dst)[i] = o;
    }
}

__global__ void conv_w(const float* __restrict__ Wq, const float* __restrict__ Wk,
                       const float* __restrict__ Wv, u16* __restrict__ Wt) {
    __shared__ float tile[64][65];
    const int jt = blockIdx.x, kt = blockIdx.y;
    const float* src = (jt < 16) ? Wq : (jt < 32) ? Wk : Wv;
    const int j0 = (jt & 15) * 64, k0 = kt * 64;
    const int t = threadIdx.x;
    for (int i = 0; i < 16; ++i) {
        int lin = t + i * 256;
        int kl = lin >> 6, jl = lin & 63;
        tile[kl][jl] = src[(size_t)(k0 + kl) * DD + j0 + jl];
    }
    __syncthreads();
    const int jg0 = jt * 64;
    for (int i = 0; i < 16; ++i) {
        int lin = t + i * 256;
        int jl = lin >> 6, kl = lin & 63;
        Wt[(size_t)(jg0 + jl) * DD + k0 + kl] = f2bf(tile[kl][jl]);
    }
}

// ---------------- QKV GEMM: R4 structure (best measured: 115 µs) ----------------
// BM=BN=256, BK=64; 512 thr = 8 waves (2M x 4N); per-wave 128x64.
// LDS 2 x (32KB A + 32KB B) = 128KB double-buffered; drain vmcnt(0) at tile boundary.
// NOTE: per-wave 128x64 tile (acc[8][4]=128 regs) forbids >2 waves/EU launch bounds
// (R9: __launch_bounds__(512,4) capped VGPR -> acc spilled to scratch -> 8x slower).
__global__ __launch_bounds__(512, 2) void gemm1_big(
    const u16* __restrict__ Xbf, const u16* __restrict__ Wt,
    const float* __restrict__ bq, const float* __restrict__ bk, const float* __restrict__ bv,
    const float* __restrict__ mask,
    u16* __restrict__ Qh, u16* __restrict__ Kh, u16* __restrict__ Vt,
    float* __restrict__ dq, float* __restrict__ dk)
{
    extern __shared__ __align__(16) char smem[];
    const int tid = threadIdx.x, l = tid & 63, wv = tid >> 6;
    const int wm = wv >> 2, wn = wv & 3;
    const int bid = blockIdx.x;
    const int xcd = bid & 7, i6 = bid >> 3;          // 768 = 8 * 96, bijective
    const int bx = xcd * 8 + i6 / 12, by = i6 % 12;
    const int row0 = bx * 256, col0 = by * 256;

    const int srow = tid >> 3;
    const int scol = ((tid & 7) ^ (srow & 7)) * 8;

    #define ABUF(p) ((char*)smem + (p) * 32768)
    #define BBUF(p) ((char*)smem + 65536 + (p) * 32768)
    #define STA(p, kt, r) load_lds16(Xbf + (size_t)(row0 + (r)*64 + srow) * DD + (kt)*64 + scol, \
                                     ABUF(p) + (r)*8192 + wv*1024)
    #define STB(p, kt, r) load_lds16(Wt + (size_t)(col0 + (r)*64 + srow) * DD + (kt)*64 + scol, \
                                     BBUF(p) + (r)*8192 + wv*1024)

    STA(0,0,0); STA(0,0,1); STA(0,0,2); STA(0,0,3);
    STB(0,0,0); STB(0,0,1); STB(0,0,2); STB(0,0,3);
    asm volatile("s_waitcnt vmcnt(0)" ::: "memory");
    __builtin_amdgcn_s_barrier();
    __builtin_amdgcn_sched_barrier(0);

    f32x4 acc[8][4] = {};
    const int arow_b = wm * 128 + (l & 15);
    const int brow_b = wn * 64 + (l & 15);
    const int cb_b = (l >> 4) * 16;
    const int lx = (l & 7) << 4;

    for (int kt = 0; kt < 16; ++kt) {
        const int p = kt & 1, pn = p ^ 1;
        const bool more = (kt + 1) < 16;
        short8 bfr[4][2];
#pragma unroll
        for (int q = 0; q < 4; ++q) {
            if (more) {
                if (q == 0)      { STA(pn, kt + 1, 0); STA(pn, kt + 1, 1); }
                else if (q == 1) { STA(pn, kt + 1, 2); STA(pn, kt + 1, 3); }
                else if (q == 2) { STB(pn, kt + 1, 0); STB(pn, kt + 1, 1); }
                else             { STB(pn, kt + 1, 2); STB(pn, kt + 1, 3); }
            }
            if (q == 0) {
#pragma unroll
                for (int nf = 0; nf < 4; ++nf) {
                    const int br = brow_b + nf * 16;
#pragma unroll
                    for (int ks = 0; ks < 2; ++ks)
                        bfr[nf][ks] = *(const short8*)(BBUF(p) + br * 128 + ((cb_b + ks * 64) ^ lx));
                }
            }
            short8 a[2][2];
#pragma unroll
            for (int i = 0; i < 2; ++i) {
                const int ar = arow_b + (q * 2 + i) * 16;
#pragma unroll
                for (int ks = 0; ks < 2; ++ks)
                    a[i][ks] = *(const short8*)(ABUF(p) + ar * 128 + ((cb_b + ks * 64) ^ lx));
            }
            __builtin_amdgcn_s_setprio(1);
#pragma unroll
            for (int i = 0; i < 2; ++i)
#pragma unroll
                for (int nf = 0; nf < 4; ++nf) {
                    acc[q*2+i][nf] = __builtin_amdgcn_mfma_f32_16x16x32_bf16(a[i][0], bfr[nf][0], acc[q*2+i][nf], 0, 0, 0);
                    acc[q*2+i][nf] = __builtin_amdgcn_mfma_f32_16x16x32_bf16(a[i][1], bfr[nf][1], acc[q*2+i][nf], 0, 0, 0);
                }
            __builtin_amdgcn_s_setprio(0);
            __builtin_amdgcn_sched_barrier(0);
        }
        asm volatile("s_waitcnt vmcnt(0)" ::: "memory");
        __builtin_amdgcn_s_barrier();
        __builtin_amdgcn_sched_barrier(0);
    }

    // ---------- fused epilogue ----------
    const int region = by >> 2;
    const int h = ((by & 3) << 2) + wn;
    const int rg = row0 + wm * 128;
    const int b = rg >> 12;
    const int sb = rg & 4095;
    const size_t bh = (size_t)(b * HH + h);
    const int dd = l & 15;
    const int jbase = ((by & 3) << 8) + wn * 64;

    if (region == 0) {
        float bias[4];
#pragma unroll
        for (int nf = 0; nf < 4; ++nf) bias[nf] = bq[jbase + nf * 16 + dd];
#pragma unroll
        for (int mf = 0; mf < 8; ++mf) {
            float ds4[4];
#pragma unroll
            for (int g = 0; g < 4; ++g) {
                const int s = sb + mf * 16 + ((l >> 4) << 2) + g;
                float dsum = 0.f;
#pragma unroll
                for (int nf = 0; nf < 4; ++nf) {
                    u16 hv = f2bf((acc[mf][nf][g] + bias[nf]) * 0.125f);
                    Qh[(bh * SS + s) * HDD + nf * 16 + dd] = hv;
                    float fv = bf2f(hv);
                    dsum += fv * fv;
                }
                dsum += __shfl_xor(dsum, 1);
                dsum += __shfl_xor(dsum, 2);
                dsum += __shfl_xor(dsum, 4);
                dsum += __shfl_xor(dsum, 8);
                ds4[g] = 0.5f * dsum;
            }
            if (dd == 0)
                *(float4*)(dq + bh * SS + sb + mf * 16 + ((l >> 4) << 2)) =
                    make_float4(ds4[0], ds4[1], ds4[2], ds4[3]);
        }
    } else if (region == 1) {
        float bias[4];
#pragma unroll
        for (int nf = 0; nf < 4; ++nf) bias[nf] = bk[jbase + nf * 16 + dd];
#pragma unroll
        for (int mf = 0; mf < 8; ++mf) {
            float ds4[4];
#pragma unroll
            for (int g = 0; g < 4; ++g) {
                const int s = sb + mf * 16 + ((l >> 4) << 2) + g;
                const float m = mask[b * SS + s];
                float dsum = 0.f;
#pragma unroll
                for (int nf = 0; nf < 4; ++nf) {
                    u16 hv = f2bf((acc[mf][nf][g] + bias[nf]) * m * 0.125f);
                    Kh[(bh * SS + s) * HDD + nf * 16 + dd] = hv;
                    float fv = bf2f(hv);
                    dsum += fv * fv;
                }
                dsum += __shfl_xor(dsum, 1);
                dsum += __shfl_xor(dsum, 2);
                dsum += __shfl_xor(dsum, 4);
                dsum += __shfl_xor(dsum, 8);
                ds4[g] = 0.5f * dsum;
            }
            if (dd == 0)
                *(float4*)(dk + bh * SS + sb + mf * 16 + ((l >> 4) << 2)) =
                    make_float4(ds4[0], ds4[1], ds4[2], ds4[3]);
        }
    } else {
        float bias[4];
#pragma unroll
        for (int nf = 0; nf < 4; ++nf) bias[nf] = bv[jbase + nf * 16 + dd];
#pragma unroll
        for (int mf = 0; mf < 8; ++mf) {
            const int s0 = sb + mf * 16 + ((l >> 4) << 2);
#pragma unroll
            for (int nf = 0; nf < 4; ++nf) {
                ushort4_t pk;
#pragma unroll
                for (int g = 0; g < 4; ++g) {
                    const float m = mask[b * SS + s0 + g];
                    pk[g] = f2bf((acc[mf][nf][g] + bias[nf]) * m);
                }
                *(ushort4_t*)(Vt + (bh * HDD + nf * 16 + dd) * SS + s0) = pk;
            }
        }
    }
    #undef ABUF
    #undef BBUF
    #undef STA
    #undef STB
}

// ---------------- kv_fused v7: online-max (no defer), rounded ksum, wv0-only vsum ----------------
// NOTE (R11 lesson): ksum MUST accumulate the same bf16-ROUNDED p values that feed the
// kv MFMA — numerator/denominator rounding errors then cancel in out = num * z.
// Unrounded ksum broke the cancellation: absmax 7.3e-4 -> 1.95e-3 (87% of threshold).
__global__ __launch_bounds__(256, 2) void kv_fused(
    const u16* __restrict__ Kh, const u16* __restrict__ Vt,
    const u16* __restrict__ projb, const float* __restrict__ dk,
    float* __restrict__ kv_part, float* __restrict__ ksum_part,
    float* __restrict__ vsum_part, float* __restrict__ lstab)
{
    extern __shared__ __align__(16) char ksm[];
    #define KLDS(b) ((char*)ksm + (b) * 8192)
    #define VLDS(b) ((char*)ksm + 24576 + (b) * 8192)
    u16* Kp = (u16*)((char*)ksm + 49152);
    const int tid = threadIdx.x, l = tid & 63, wv = tid >> 6;
    const int ck = blockIdx.x, bh = blockIdx.y;
    short8 pb[4][2];
#pragma unroll
    for (int nf = 0; nf < 4; ++nf)
#pragma unroll
        for (int ks = 0; ks < 2; ++ks)
            pb[nf][ks] = *(const short8*)(projb + (wv * 64 + nf * 16 + (l & 15)) * HDD + ks * 32 + (l >> 4) * 8);
    const size_t sbase = (size_t)bh * SS + ck * 512;

    #define KSTAGE(buf, it8) do { \
        const int s0_ = (it8) * 64; \
        _Pragma("unroll") \
        for (int c = 0; c < 2; ++c) { \
            const int rb = wv * 16 + c * 8; \
            const int r = rb + (l >> 3); \
            const int sc = ((l & 7) ^ (r & 7)) * 8; \
            load_lds16(Kh + (sbase + s0_ + r) * HDD + sc, KLDS(buf) + rb * 128); \
        } \
    } while (0)
    #define VSTAGE(buf, it8) do { \
        const int s0_ = (it8) * 64; \
        _Pragma("unroll") \
        for (int c = 0; c < 2; ++c) { \
            const int rb = wv * 16 + c * 8; \
            const int r = rb + (l >> 3); \
            const int sc = ((l & 7) ^ (r & 7)) * 8; \
            load_lds16(Vt + ((size_t)bh * HDD + r) * SS + ck * 512 + s0_ + sc, VLDS(buf) + rb * 128); \
        } \
    } while (0)

    float mrun = -3.0e38f;
    f32x4 acc[4][4] = {};
    float ksc[4] = {0.f, 0.f, 0.f, 0.f};
    float vsc[4] = {0.f, 0.f, 0.f, 0.f};
    KSTAGE(0, 0); VSTAGE(0, 0);
    for (int it = 0; it < 8; ++it) {
        if (it + 1 < 8) {
            KSTAGE((it + 1) % 3, it + 1);
            VSTAGE((it + 1) % 3, it + 1);
            asm volatile("s_waitcnt vmcnt(4)" ::: "memory");
        } else {
            asm volatile("s_waitcnt vmcnt(0)" ::: "memory");
        }
        __syncthreads();
        const int bs = it % 3;
        const int s0 = it * 64;
        f32x4 u4[4][4];
#pragma unroll
        for (int sf = 0; sf < 4; ++sf) {
#pragma unroll
            for (int nf = 0; nf < 4; ++nf) u4[sf][nf] = (f32x4){0.f, 0.f, 0.f, 0.f};
            const int s = sf * 16 + (l & 15);
#pragma unroll
            for (int ks = 0; ks < 2; ++ks) {
                short8 ak = *(const short8*)(KLDS(bs) + s * 128 + ((ks * 64 + (l >> 4) * 16) ^ ((s & 7) << 4)));
#pragma unroll
                for (int nf = 0; nf < 4; ++nf)
                    u4[sf][nf] = __builtin_amdgcn_mfma_f32_16x16x32_bf16(ak, pb[nf][ks], u4[sf][nf], 0, 0, 0);
            }
        }
        float pmax = -3.0e38f;
#pragma unroll
        for (int sf = 0; sf < 4; ++sf)
#pragma unroll
            for (int nf = 0; nf < 4; ++nf)
#pragma unroll
                for (int g = 0; g < 4; ++g) pmax = fmaxf(pmax, u4[sf][nf][g]);
#pragma unroll
        for (int o = 1; o < 64; o <<= 1) pmax = fmaxf(pmax, __shfl_xor(pmax, o));
        if (pmax > mrun) {                       // wave-uniform, plain online-max
            const float fac = __expf(mrun - pmax);
            mrun = pmax;
#pragma unroll
            for (int mf = 0; mf < 4; ++mf)
#pragma unroll
                for (int nf = 0; nf < 4; ++nf)
#pragma unroll
                    for (int g = 0; g < 4; ++g) acc[mf][nf][g] *= fac;
#pragma unroll
            for (int nf = 0; nf < 4; ++nf) ksc[nf] *= fac;
        }
#pragma unroll
        for (int sf = 0; sf < 4; ++sf) {
            const int srow = sf * 16 + (l >> 4) * 4;
            const float4 dkv = *(const float4*)(dk + sbase + s0 + srow);
            const float b0 = dkv.x + mrun, b1 = dkv.y + mrun, b2 = dkv.z + mrun, b3 = dkv.w + mrun;
#pragma unroll
            for (int nf = 0; nf < 4; ++nf) {
                const int m = wv * 64 + nf * 16 + (l & 15);
                u16 h0 = f2bf(__expf(u4[sf][nf][0] - b0));
                u16 h1 = f2bf(__expf(u4[sf][nf][1] - b1));
                u16 h2 = f2bf(__expf(u4[sf][nf][2] - b2));
                u16 h3 = f2bf(__expf(u4[sf][nf][3] - b3));
                ksc[nf] += (bf2f(h0) + bf2f(h1)) + (bf2f(h2) + bf2f(h3));  // ROUNDED: matches kv
                uint2 w; w.x = (u32)h0 | ((u32)h1 << 16); w.y = (u32)h2 | ((u32)h3 << 16);
                *(uint2*)((char*)Kp + m * 128 + ((srow * 2) ^ ((m & 7) << 4))) = w;
            }
        }
        __syncthreads();
#pragma unroll
        for (int ks = 0; ks < 2; ++ks) {
            short8 am[4], bv8[4];
#pragma unroll
            for (int mf = 0; mf < 4; ++mf) {
                const int m = wv * 64 + mf * 16 + (l & 15);
                am[mf] = *(const short8*)((const char*)Kp + m * 128 + ((ks * 64 + (l >> 4) * 16) ^ ((m & 7) << 4)));
            }
#pragma unroll
            for (int nf = 0; nf < 4; ++nf) {
                const int d = nf * 16 + (l & 15);
                bv8[nf] = *(const short8*)(VLDS(bs) + d * 128 + ((ks * 64 + (l >> 4) * 16) ^ ((d & 7) << 4)));
            }
            if (wv == 0) {                         // vsum identical across waves: compute once
#pragma unroll
                for (int nf = 0; nf < 4; ++nf) {
                    float vs = 0.f;
#pragma unroll
                    for (int e = 0; e < 8; ++e) vs += bf2f((u16)bv8[nf][e]);
                    vsc[nf] += vs;
                }
            }
#pragma unroll
            for (int mf = 0; mf < 4; ++mf)
#pragma unroll
                for (int nf = 0; nf < 4; ++nf)
                    acc[mf][nf] = __builtin_amdgcn_mfma_f32_16x16x32_bf16(am[mf], bv8[nf], acc[mf][nf], 0, 0, 0);
        }
    }
    if (l == 0) lstab[((size_t)ck * BHN + bh) * 4 + wv] = mrun;
    const size_t pbase = (size_t)ck * BHN + bh;
#pragma unroll
    for (int nf = 0; nf < 4; ++nf) {
        float v = ksc[nf];
        v += __shfl_xor(v, 16);
        v += __shfl_xor(v, 32);
        if (l < 16) ksum_part[pbase * MM + wv * 64 + nf * 16 + l] = v;
        if (wv == 0) {
            float w = vsc[nf];
            w += __shfl_xor(w, 16);
            w += __shfl_xor(w, 32);
            if (l < 16) vsum_part[pbase * HDD + nf * 16 + l] = w;
        }
    }
#pragma unroll
    for (int mf = 0; mf < 4; ++mf)
#pragma unroll
        for (int nf = 0; nf < 4; ++nf)
            *(f32x4*)(kv_part + (pbase * HDD + nf * 16 + (l & 15)) * MM + wv * 64 + mf * 16 + (l >> 4) * 4) = acc[mf][nf];
    #undef KLDS
    #undef VLDS
    #undef KSTAGE
    #undef VSTAGE
}

// ---------------- reduceB3: rescale partials by exp(lstab - G), add eps terms ----------------
__global__ void reduceB3(const float* __restrict__ kv_part, const float* __restrict__ ksum_part,
                         const float* __restrict__ vsum_part, const float* __restrict__ lstab,
                         u16* __restrict__ Bmat) {
    __shared__ float f[8][4];
    const int bh = blockIdx.x, n = blockIdx.y, t = threadIdx.x;
    if (t < 32) {
        float lv = lstab[((size_t)(t >> 2) * BHN + bh) * 4 + (t & 3)];
        float g = lv;
#pragma unroll
        for (int o = 1; o < 32; o <<= 1) g = fmaxf(g, __shfl_xor(g, o));
        f[t >> 2][t & 3] = __expf(lv - g);
    }
    __syncthreads();
    const int grp = t >> 6;
    float s = 0.f;
    if (n < 64) {
        float vsg = 0.f;
#pragma unroll
        for (int ck = 0; ck < 8; ++ck) {
            vsg += vsum_part[((size_t)ck * BHN + bh) * HDD + n];
            s += kv_part[(((size_t)ck * BHN + bh) * HDD + n) * MM + t] * f[ck][grp];
        }
        s = 0.0625f * (s + 1e-4f * vsg);
    } else if (n == 64) {
#pragma unroll
        for (int ck = 0; ck < 8; ++ck)
            s += ksum_part[((size_t)ck * BHN + bh) * MM + t] * f[ck][grp];
        s = 0.0625f * (s + 1e-4f * 4096.0f);
    }
    Bmat[((size_t)bh * 80 + n) * MM + t] = (n <= 64) ? f2bf(s) : (u16)0;
}

// ---------------- out_fused v2: QBLK=64, B-frags direct from L2, no Blds ----------------
__global__ __launch_bounds__(256) void out_fused(
    const u16* __restrict__ Qh, const u16* __restrict__ projb,
    const float* __restrict__ dq, const u16* __restrict__ Bmat,
    float* __restrict__ out)
{
    __shared__ __align__(16) u16 Qlds[64 * 64];
    __shared__ __align__(16) u16 qlds[64 * 256];
    __shared__ float red[4][64];
    const int tid = threadIdx.x, l = tid & 63, wv = tid >> 6;
    const int rt = blockIdx.x, bh = blockIdx.y;
    const size_t srowbase = (size_t)bh * SS + rt * 64;
#pragma unroll
    for (int c = 0; c < 2; ++c) {
        const int rb = wv * 16 + c * 8;
        const int r = rb + (l >> 3);
        load_lds16(Qh + (srowbase + r) * HDD + (((l & 7) ^ (r & 7)) * 8), (char*)Qlds + rb * 128);
    }
    short8 pa[4][2];
#pragma unroll
    for (int mf = 0; mf < 4; ++mf)
#pragma unroll
        for (int ks = 0; ks < 2; ++ks)
            pa[mf][ks] = *(const short8*)(projb + (wv * 64 + mf * 16 + (l & 15)) * HDD + ks * 32 + (l >> 4) * 8);
    __syncthreads();
    f32x4 u[4][4] = {};
#pragma unroll
    for (int ks = 0; ks < 2; ++ks) {
        short8 bq8[4];
#pragma unroll
        for (int nf = 0; nf < 4; ++nf) {
            const int s = nf * 16 + (l & 15);
            bq8[nf] = *(const short8*)((const char*)Qlds + s * 128 + ((ks * 64 + (l >> 4) * 16) ^ ((s & 7) << 4)));
        }
#pragma unroll
        for (int mf = 0; mf < 4; ++mf)
#pragma unroll
            for (int nf = 0; nf < 4; ++nf)
                u[mf][nf] = __builtin_amdgcn_mfma_f32_16x16x32_bf16(pa[mf][ks], bq8[nf], u[mf][nf], 0, 0, 0);
    }
#pragma unroll
    for (int nf = 0; nf < 4; ++nf) {
        float v = -3.0e38f;
#pragma unroll
        for (int mf = 0; mf < 4; ++mf)
#pragma unroll
            for (int g = 0; g < 4; ++g) v = fmaxf(v, u[mf][nf][g]);
        v = fmaxf(v, __shfl_xor(v, 16));
        v = fmaxf(v, __shfl_xor(v, 32));
        if ((l >> 4) == 0) red[wv][nf * 16 + l] = v;
    }
    __syncthreads();
#pragma unroll
    for (int nf = 0; nf < 4; ++nf) {
        const int s = nf * 16 + (l & 15);
        const float mx = fmaxf(fmaxf(red[0][s], red[1][s]), fmaxf(red[2][s], red[3][s]));
        const float dgmx = dq[srowbase + s] + mx;    // hoisted per-s bias
#pragma unroll
        for (int mf = 0; mf < 4; ++mf) {
            u16 h0 = f2bf(0.0625f * (__expf(u[mf][nf][0] - dgmx) + 1e-4f));
            u16 h1 = f2bf(0.0625f * (__expf(u[mf][nf][1] - dgmx) + 1e-4f));
            u16 h2 = f2bf(0.0625f * (__expf(u[mf][nf][2] - dgmx) + 1e-4f));
            u16 h3 = f2bf(0.0625f * (__expf(u[mf][nf][3] - dgmx) + 1e-4f));
            uint2 w; w.x = (u32)h0 | ((u32)h1 << 16); w.y = (u32)h2 | ((u32)h3 << 16);
            const int mb = (wv * 64 + mf * 16 + (l >> 4) * 4) * 2;
            *(uint2*)((char*)qlds + s * 512 + (mb ^ ((s & 7) << 4))) = w;
        }
    }
    __syncthreads();
    const u16* bbase = Bmat + (size_t)bh * 20480;
    f32x4 acc[4][2] = {};
#pragma unroll
    for (int kt = 0; kt < 8; ++kt) {
        short8 aq[4], bb[2];
#pragma unroll
        for (int mf = 0; mf < 4; ++mf) {
            const int s = mf * 16 + (l & 15);
            aq[mf] = *(const short8*)((const char*)qlds + s * 512 + ((kt * 64 + (l >> 4) * 16) ^ ((s & 7) << 4)));
        }
        bb[0] = *(const short8*)(bbase + (wv * 16 + (l & 15)) * 256 + kt * 32 + (l >> 4) * 8);
        bb[1] = *(const short8*)(bbase + (64 + (l & 15)) * 256 + kt * 32 + (l >> 4) * 8);
#pragma unroll
        for (int mf = 0; mf < 4; ++mf)
#pragma unroll
            for (int nf = 0; nf < 2; ++nf)
                acc[mf][nf] = __builtin_amdgcn_mfma_f32_16x16x32_bf16(aq[mf], bb[nf], acc[mf][nf], 0, 0, 0);
    }
    const int b = bh >> 4, h = bh & 15;
#pragma unroll
    for (int mf = 0; mf < 4; ++mf) {
#pragma unroll
        for (int g = 0; g < 4; ++g) {
            const float den = __shfl(acc[mf][1][g], (l & 48));
            const float z = 1.0f / (den + 1e-6f);
            const int s = rt * 64 + mf * 16 + (l >> 4) * 4 + g;
            out[((size_t)b * SS + s) * DD + h * HDD + wv * 16 + (l & 15)] = acc[mf][0][g] * z;
        }
    }
}

// ---------------- launcher ----------------
extern "C" void kernel_launch(void* const* d_in, const int* in_sizes, int n_in,
                              void* d_out, int out_size, void* d_ws, size_t ws_size,
                              hipStream_t stream)
{
    const float* X    = (const float*)d_in[0];
    const float* mask = (const float*)d_in[1];
    const float* Wq   = (const float*)d_in[2];
    const float* bq   = (const float*)d_in[3];
    const float* Wk   = (const float*)d_in[4];
    const float* bk   = (const float*)d_in[5];
    const float* Wv   = (const float*)d_in[6];
    const float* bv   = (const float*)d_in[7];
    const float* proj = (const float*)d_in[8];
    float* out = (float*)d_out;

    char* p = (char*)d_ws;
    u16* Xbf = (u16*)p;                            // 32 MB (aliased by kv_part after gemm1)
    float* kv_part = (float*)p; p += 33554432;
    u16* Wt = (u16*)p;    p += 6291456;
    u16* projb = (u16*)p; p += 32768;
    u16* Qh = (u16*)p;    p += 33554432;
    u16* Kh = (u16*)p;    p += 33554432;
    u16* Vt = (u16*)p;    p += 33554432;
    float* dq = (float*)p; p += 1048576;
    float* dk = (float*)p; p += 1048576;
    float* ksum_part = (float*)p; p += 524288;
    u16* Bmat = (u16*)p;  p += 2621440;
    float* vsum_part = (float*)p; p += 131072;     // [8][64][64] f32
    float* lstab = (float*)p; p += 8192;           // [8][64][4] f32
    if (ws_size < 145924096ull) return;

    hipFuncSetAttribute((const void*)gemm1_big, hipFuncAttributeMaxDynamicSharedMemorySize, 131072);
    hipFuncSetAttribute((const void*)kv_fused, hipFuncAttributeMaxDynamicSharedMemorySize, 81920);

    conv_bf16<<<16384, 256, 0, stream>>>(X, Xbf, 4194304);
    conv_w<<<dim3(48, 16), 256, 0, stream>>>(Wq, Wk, Wv, Wt);
    conv_bf16<<<16, 256, 0, stream>>>(proj, projb, 4096);
    gemm1_big<<<768, 512, 131072, stream>>>(Xbf, Wt, bq, bk, bv, mask, Qh, Kh, Vt, dq, dk);
    kv_fused<<<dim3(8, 64), 256, 81920, stream>>>(Kh, Vt, projb, dk, kv_part, ksum_part, vsum_part, lstab);
    reduceB3<<<dim3(64, 80), 256, 0, stream>>>(kv_part, ksum_part, vsum_part, lstab, Bmat);
    out_fused<<<dim3(64, 64), 256, 0, stream>>>(Qh, projb, dq, Bmat, out);
}

// Round 13
// 245.711 us; speedup vs baseline: 4.1286x; 1.0181x over previous
//
#include <hip/hip_runtime.h>
#include <stdint.h>

#define DEVI static __device__ __forceinline__

typedef unsigned short u16;
typedef unsigned int u32;
typedef __attribute__((ext_vector_type(8))) short short8;
typedef __attribute__((ext_vector_type(4))) float f32x4;
typedef __attribute__((ext_vector_type(4))) unsigned short ushort4_t;

#define BB 4
#define SS 4096
#define DD 1024
#define HH 16
#define HDD 64
#define MM 256
#define BHN 64

DEVI u16 f2bf(float f) {
    u32 u = __float_as_uint(f);
    u += 0x7fffu + ((u >> 16) & 1u);
    return (u16)(u >> 16);
}
DEVI float bf2f(u16 h) { return __uint_as_float(((u32)h) << 16); }

typedef __attribute__((address_space(1))) const unsigned int as1_u32;
typedef __attribute__((address_space(3))) unsigned int as3_u32;
DEVI void load_lds16(const void* g, void* lds) {
    __builtin_amdgcn_global_load_lds((as1_u32*)g, (as3_u32*)lds, 16, 0, 0);
}

// ---------------- conversion kernels ----------------

__global__ void conv_bf16(const float* __restrict__ src, u16* __restrict__ dst, int n4) {
    for (int i = blockIdx.x * 256 + threadIdx.x; i < n4; i += 2048 * 256) {
        float4 v = reinterpret_cast<const float4*>(src)[i];
        ushort4_t o = { f2bf(v.x), f2bf(v.y), f2bf(v.z), f2bf(v.w) };
        reinterpret_cast<ushort4_t*>(dst)[i] = o;
    }
}

__global__ void conv_w(const float* __restrict__ Wq, const float* __restrict__ Wk,
                       const float* __restrict__ Wv, u16* __restrict__ Wt) {
    __shared__ float tile[64][65];
    const int jt = blockIdx.x, kt = blockIdx.y;
    const float* src = (jt < 16) ? Wq : (jt < 32) ? Wk : Wv;
    const int j0 = (jt & 15) * 64, k0 = kt * 64;
    const int t = threadIdx.x;
    for (int i = 0; i < 16; ++i) {
        int lin = t + i * 256;
        int kl = lin >> 6, jl = lin & 63;
        tile[kl][jl] = src[(size_t)(k0 + kl) * DD + j0 + jl];
    }
    __syncthreads();
    const int jg0 = jt * 64;
    for (int i = 0; i < 16; ++i) {
        int lin = t + i * 256;
        int jl = lin >> 6, kl = lin & 63;
        Wt[(size_t)(jg0 + jl) * DD + k0 + kl] = f2bf(tile[kl][jl]);
    }
}

// ---------------- QKV GEMM: R4 structure (best measured: 912 TF) ----------------
// BM=BN=256, BK=64; 512 thr = 8 waves (2M x 4N); per-wave 128x64.
// LDS 2 x (32KB A + 32KB B) = 128KB double-buffered; drain vmcnt(0) at tile boundary.
// Block order: by-major within XCD (8 consecutive blocks share the B-panel; the 8
// cycling A-panels = 4MB = exactly one per-XCD L2).
// NOTE: per-wave 128x64 tile (acc[8][4]=128 regs) forbids >2 waves/EU launch bounds
// (R9: __launch_bounds__(512,4) capped VGPR -> acc spilled to scratch -> 8x slower).
__global__ __launch_bounds__(512, 2) void gemm1_big(
    const u16* __restrict__ Xbf, const u16* __restrict__ Wt,
    const float* __restrict__ bq, const float* __restrict__ bk, const float* __restrict__ bv,
    const float* __restrict__ mask,
    u16* __restrict__ Qh, u16* __restrict__ Kh, u16* __restrict__ Vt,
    float* __restrict__ dq, float* __restrict__ dk)
{
    extern __shared__ __align__(16) char smem[];
    const int tid = threadIdx.x, l = tid & 63, wv = tid >> 6;
    const int wm = wv >> 2, wn = wv & 3;
    const int bid = blockIdx.x;
    const int xcd = bid & 7, i6 = bid >> 3;          // 768 = 8 * 96, bijective
    const int bx = xcd * 8 + (i6 & 7), by = i6 >> 3; // by-major: B-panel hot 8 blocks
    const int row0 = bx * 256, col0 = by * 256;

    const int srow = tid >> 3;
    const int scol = ((tid & 7) ^ (srow & 7)) * 8;

    #define ABUF(p) ((char*)smem + (p) * 32768)
    #define BBUF(p) ((char*)smem + 65536 + (p) * 32768)
    #define STA(p, kt, r) load_lds16(Xbf + (size_t)(row0 + (r)*64 + srow) * DD + (kt)*64 + scol, \
                                     ABUF(p) + (r)*8192 + wv*1024)
    #define STB(p, kt, r) load_lds16(Wt + (size_t)(col0 + (r)*64 + srow) * DD + (kt)*64 + scol, \
                                     BBUF(p) + (r)*8192 + wv*1024)

    STA(0,0,0); STA(0,0,1); STA(0,0,2); STA(0,0,3);
    STB(0,0,0); STB(0,0,1); STB(0,0,2); STB(0,0,3);
    asm volatile("s_waitcnt vmcnt(0)" ::: "memory");
    __builtin_amdgcn_s_barrier();
    __builtin_amdgcn_sched_barrier(0);

    f32x4 acc[8][4] = {};
    const int arow_b = wm * 128 + (l & 15);
    const int brow_b = wn * 64 + (l & 15);
    const int cb_b = (l >> 4) * 16;
    const int lx = (l & 7) << 4;

    for (int kt = 0; kt < 16; ++kt) {
        const int p = kt & 1, pn = p ^ 1;
        const bool more = (kt + 1) < 16;
        short8 bfr[4][2];
#pragma unroll
        for (int q = 0; q < 4; ++q) {
            if (more) {
                if (q == 0)      { STA(pn, kt + 1, 0); STA(pn, kt + 1, 1); }
                else if (q == 1) { STA(pn, kt + 1, 2); STA(pn, kt + 1, 3); }
                else if (q == 2) { STB(pn, kt + 1, 0); STB(pn, kt + 1, 1); }
                else             { STB(pn, kt + 1, 2); STB(pn, kt + 1, 3); }
            }
            if (q == 0) {
#pragma unroll
                for (int nf = 0; nf < 4; ++nf) {
                    const int br = brow_b + nf * 16;
#pragma unroll
                    for (int ks = 0; ks < 2; ++ks)
                        bfr[nf][ks] = *(const short8*)(BBUF(p) + br * 128 + ((cb_b + ks * 64) ^ lx));
                }
            }
            short8 a[2][2];
#pragma unroll
            for (int i = 0; i < 2; ++i) {
                const int ar = arow_b + (q * 2 + i) * 16;
#pragma unroll
                for (int ks = 0; ks < 2; ++ks)
                    a[i][ks] = *(const short8*)(ABUF(p) + ar * 128 + ((cb_b + ks * 64) ^ lx));
            }
            __builtin_amdgcn_s_setprio(1);
#pragma unroll
            for (int i = 0; i < 2; ++i)
#pragma unroll
                for (int nf = 0; nf < 4; ++nf) {
                    acc[q*2+i][nf] = __builtin_amdgcn_mfma_f32_16x16x32_bf16(a[i][0], bfr[nf][0], acc[q*2+i][nf], 0, 0, 0);
                    acc[q*2+i][nf] = __builtin_amdgcn_mfma_f32_16x16x32_bf16(a[i][1], bfr[nf][1], acc[q*2+i][nf], 0, 0, 0);
                }
            __builtin_amdgcn_s_setprio(0);
            __builtin_amdgcn_sched_barrier(0);
        }
        asm volatile("s_waitcnt vmcnt(0)" ::: "memory");
        __builtin_amdgcn_s_barrier();
        __builtin_amdgcn_sched_barrier(0);
    }

    // ---------- fused epilogue ----------
    const int region = by >> 2;
    const int h = ((by & 3) << 2) + wn;
    const int rg = row0 + wm * 128;
    const int b = rg >> 12;
    const int sb = rg & 4095;
    const size_t bh = (size_t)(b * HH + h);
    const int dd = l & 15;
    const int jbase = ((by & 3) << 8) + wn * 64;

    if (region == 0) {
        float bias[4];
#pragma unroll
        for (int nf = 0; nf < 4; ++nf) bias[nf] = bq[jbase + nf * 16 + dd];
#pragma unroll
        for (int mf = 0; mf < 8; ++mf) {
            float ds4[4];
#pragma unroll
            for (int g = 0; g < 4; ++g) {
                const int s = sb + mf * 16 + ((l >> 4) << 2) + g;
                float dsum = 0.f;
#pragma unroll
                for (int nf = 0; nf < 4; ++nf) {
                    u16 hv = f2bf((acc[mf][nf][g] + bias[nf]) * 0.125f);
                    Qh[(bh * SS + s) * HDD + nf * 16 + dd] = hv;
                    float fv = bf2f(hv);
                    dsum += fv * fv;
                }
                dsum += __shfl_xor(dsum, 1);
                dsum += __shfl_xor(dsum, 2);
                dsum += __shfl_xor(dsum, 4);
                dsum += __shfl_xor(dsum, 8);
                ds4[g] = 0.5f * dsum;
            }
            if (dd == 0)
                *(float4*)(dq + bh * SS + sb + mf * 16 + ((l >> 4) << 2)) =
                    make_float4(ds4[0], ds4[1], ds4[2], ds4[3]);
        }
    } else if (region == 1) {
        float bias[4];
#pragma unroll
        for (int nf = 0; nf < 4; ++nf) bias[nf] = bk[jbase + nf * 16 + dd];
#pragma unroll
        for (int mf = 0; mf < 8; ++mf) {
            float ds4[4];
#pragma unroll
            for (int g = 0; g < 4; ++g) {
                const int s = sb + mf * 16 + ((l >> 4) << 2) + g;
                const float m = mask[b * SS + s];
                float dsum = 0.f;
#pragma unroll
                for (int nf = 0; nf < 4; ++nf) {
                    u16 hv = f2bf((acc[mf][nf][g] + bias[nf]) * m * 0.125f);
                    Kh[(bh * SS + s) * HDD + nf * 16 + dd] = hv;
                    float fv = bf2f(hv);
                    dsum += fv * fv;
                }
                dsum += __shfl_xor(dsum, 1);
                dsum += __shfl_xor(dsum, 2);
                dsum += __shfl_xor(dsum, 4);
                dsum += __shfl_xor(dsum, 8);
                ds4[g] = 0.5f * dsum;
            }
            if (dd == 0)
                *(float4*)(dk + bh * SS + sb + mf * 16 + ((l >> 4) << 2)) =
                    make_float4(ds4[0], ds4[1], ds4[2], ds4[3]);
        }
    } else {
        float bias[4];
#pragma unroll
        for (int nf = 0; nf < 4; ++nf) bias[nf] = bv[jbase + nf * 16 + dd];
#pragma unroll
        for (int mf = 0; mf < 8; ++mf) {
            const int s0 = sb + mf * 16 + ((l >> 4) << 2);
#pragma unroll
            for (int nf = 0; nf < 4; ++nf) {
                ushort4_t pk;
#pragma unroll
                for (int g = 0; g < 4; ++g) {
                    const float m = mask[b * SS + s0 + g];
                    pk[g] = f2bf((acc[mf][nf][g] + bias[nf]) * m);
                }
                *(ushort4_t*)(Vt + (bh * HDD + nf * 16 + dd) * SS + s0) = pk;
            }
        }
    }
    #undef ABUF
    #undef BBUF
    #undef STA
    #undef STB
}

// ---------------- kv_fused v7: online-max (no defer), rounded ksum, wv0-only vsum ----------------
// NOTE (R11 lesson): ksum MUST accumulate the same bf16-ROUNDED p values that feed the
// kv MFMA — numerator/denominator rounding errors then cancel in out = num * z.
// Unrounded ksum broke the cancellation: absmax 7.3e-4 -> 1.95e-3 (87% of threshold).
__global__ __launch_bounds__(256, 2) void kv_fused(
    const u16* __restrict__ Kh, const u16* __restrict__ Vt,
    const u16* __restrict__ projb, const float* __restrict__ dk,
    float* __restrict__ kv_part, float* __restrict__ ksum_part,
    float* __restrict__ vsum_part, float* __restrict__ lstab)
{
    extern __shared__ __align__(16) char ksm[];
    #define KLDS(b) ((char*)ksm + (b) * 8192)
    #define VLDS(b) ((char*)ksm + 24576 + (b) * 8192)
    u16* Kp = (u16*)((char*)ksm + 49152);
    const int tid = threadIdx.x, l = tid & 63, wv = tid >> 6;
    const int ck = blockIdx.x, bh = blockIdx.y;
    short8 pb[4][2];
#pragma unroll
    for (int nf = 0; nf < 4; ++nf)
#pragma unroll
        for (int ks = 0; ks < 2; ++ks)
            pb[nf][ks] = *(const short8*)(projb + (wv * 64 + nf * 16 + (l & 15)) * HDD + ks * 32 + (l >> 4) * 8);
    const size_t sbase = (size_t)bh * SS + ck * 512;

    #define KSTAGE(buf, it8) do { \
        const int s0_ = (it8) * 64; \
        _Pragma("unroll") \
        for (int c = 0; c < 2; ++c) { \
            const int rb = wv * 16 + c * 8; \
            const int r = rb + (l >> 3); \
            const int sc = ((l & 7) ^ (r & 7)) * 8; \
            load_lds16(Kh + (sbase + s0_ + r) * HDD + sc, KLDS(buf) + rb * 128); \
        } \
    } while (0)
    #define VSTAGE(buf, it8) do { \
        const int s0_ = (it8) * 64; \
        _Pragma("unroll") \
        for (int c = 0; c < 2; ++c) { \
            const int rb = wv * 16 + c * 8; \
            const int r = rb + (l >> 3); \
            const int sc = ((l & 7) ^ (r & 7)) * 8; \
            load_lds16(Vt + ((size_t)bh * HDD + r) * SS + ck * 512 + s0_ + sc, VLDS(buf) + rb * 128); \
        } \
    } while (0)

    float mrun = -3.0e38f;
    f32x4 acc[4][4] = {};
    float ksc[4] = {0.f, 0.f, 0.f, 0.f};
    float vsc[4] = {0.f, 0.f, 0.f, 0.f};
    KSTAGE(0, 0); VSTAGE(0, 0);
    for (int it = 0; it < 8; ++it) {
        if (it + 1 < 8) {
            KSTAGE((it + 1) % 3, it + 1);
            VSTAGE((it + 1) % 3, it + 1);
            asm volatile("s_waitcnt vmcnt(4)" ::: "memory");
        } else {
            asm volatile("s_waitcnt vmcnt(0)" ::: "memory");
        }
        __syncthreads();
        const int bs = it % 3;
        const int s0 = it * 64;
        f32x4 u4[4][4];
#pragma unroll
        for (int sf = 0; sf < 4; ++sf) {
#pragma unroll
            for (int nf = 0; nf < 4; ++nf) u4[sf][nf] = (f32x4){0.f, 0.f, 0.f, 0.f};
            const int s = sf * 16 + (l & 15);
#pragma unroll
            for (int ks = 0; ks < 2; ++ks) {
                short8 ak = *(const short8*)(KLDS(bs) + s * 128 + ((ks * 64 + (l >> 4) * 16) ^ ((s & 7) << 4)));
#pragma unroll
                for (int nf = 0; nf < 4; ++nf)
                    u4[sf][nf] = __builtin_amdgcn_mfma_f32_16x16x32_bf16(ak, pb[nf][ks], u4[sf][nf], 0, 0, 0);
            }
        }
        float pmax = -3.0e38f;
#pragma unroll
        for (int sf = 0; sf < 4; ++sf)
#pragma unroll
            for (int nf = 0; nf < 4; ++nf)
#pragma unroll
                for (int g = 0; g < 4; ++g) pmax = fmaxf(pmax, u4[sf][nf][g]);
#pragma unroll
        for (int o = 1; o < 64; o <<= 1) pmax = fmaxf(pmax, __shfl_xor(pmax, o));
        if (pmax > mrun) {                       // wave-uniform, plain online-max
            const float fac = __expf(mrun - pmax);
            mrun = pmax;
#pragma unroll
            for (int mf = 0; mf < 4; ++mf)
#pragma unroll
                for (int nf = 0; nf < 4; ++nf)
#pragma unroll
                    for (int g = 0; g < 4; ++g) acc[mf][nf][g] *= fac;
#pragma unroll
            for (int nf = 0; nf < 4; ++nf) ksc[nf] *= fac;
        }
#pragma unroll
        for (int sf = 0; sf < 4; ++sf) {
            const int srow = sf * 16 + (l >> 4) * 4;
            const float4 dkv = *(const float4*)(dk + sbase + s0 + srow);
            const float b0 = dkv.x + mrun, b1 = dkv.y + mrun, b2 = dkv.z + mrun, b3 = dkv.w + mrun;
#pragma unroll
            for (int nf = 0; nf < 4; ++nf) {
                const int m = wv * 64 + nf * 16 + (l & 15);
                u16 h0 = f2bf(__expf(u4[sf][nf][0] - b0));
                u16 h1 = f2bf(__expf(u4[sf][nf][1] - b1));
                u16 h2 = f2bf(__expf(u4[sf][nf][2] - b2));
                u16 h3 = f2bf(__expf(u4[sf][nf][3] - b3));
                ksc[nf] += (bf2f(h0) + bf2f(h1)) + (bf2f(h2) + bf2f(h3));  // ROUNDED: matches kv
                uint2 w; w.x = (u32)h0 | ((u32)h1 << 16); w.y = (u32)h2 | ((u32)h3 << 16);
                *(uint2*)((char*)Kp + m * 128 + ((srow * 2) ^ ((m & 7) << 4))) = w;
            }
        }
        __syncthreads();
#pragma unroll
        for (int ks = 0; ks < 2; ++ks) {
            short8 am[4], bv8[4];
#pragma unroll
            for (int mf = 0; mf < 4; ++mf) {
                const int m = wv * 64 + mf * 16 + (l & 15);
                am[mf] = *(const short8*)((const char*)Kp + m * 128 + ((ks * 64 + (l >> 4) * 16) ^ ((m & 7) << 4)));
            }
#pragma unroll
            for (int nf = 0; nf < 4; ++nf) {
                const int d = nf * 16 + (l & 15);
                bv8[nf] = *(const short8*)(VLDS(bs) + d * 128 + ((ks * 64 + (l >> 4) * 16) ^ ((d & 7) << 4)));
            }
            if (wv == 0) {                         // vsum identical across waves: compute once
#pragma unroll
                for (int nf = 0; nf < 4; ++nf) {
                    float vs = 0.f;
#pragma unroll
                    for (int e = 0; e < 8; ++e) vs += bf2f((u16)bv8[nf][e]);
                    vsc[nf] += vs;
                }
            }
#pragma unroll
            for (int mf = 0; mf < 4; ++mf)
#pragma unroll
                for (int nf = 0; nf < 4; ++nf)
                    acc[mf][nf] = __builtin_amdgcn_mfma_f32_16x16x32_bf16(am[mf], bv8[nf], acc[mf][nf], 0, 0, 0);
        }
    }
    if (l == 0) lstab[((size_t)ck * BHN + bh) * 4 + wv] = mrun;
    const size_t pbase = (size_t)ck * BHN + bh;
#pragma unroll
    for (int nf = 0; nf < 4; ++nf) {
        float v = ksc[nf];
        v += __shfl_xor(v, 16);
        v += __shfl_xor(v, 32);
        if (l < 16) ksum_part[pbase * MM + wv * 64 + nf * 16 + l] = v;
        if (wv == 0) {
            float w = vsc[nf];
            w += __shfl_xor(w, 16);
            w += __shfl_xor(w, 32);
            if (l < 16) vsum_part[pbase * HDD + nf * 16 + l] = w;
        }
    }
#pragma unroll
    for (int mf = 0; mf < 4; ++mf)
#pragma unroll
        for (int nf = 0; nf < 4; ++nf)
            *(f32x4*)(kv_part + (pbase * HDD + nf * 16 + (l & 15)) * MM + wv * 64 + mf * 16 + (l >> 4) * 4) = acc[mf][nf];
    #undef KLDS
    #undef VLDS
    #undef KSTAGE
    #undef VSTAGE
}

// ---------------- reduceB3: rescale partials by exp(lstab - G), add eps terms ----------------
__global__ void reduceB3(const float* __restrict__ kv_part, const float* __restrict__ ksum_part,
                         const float* __restrict__ vsum_part, const float* __restrict__ lstab,
                         u16* __restrict__ Bmat) {
    __shared__ float f[8][4];
    const int bh = blockIdx.x, n = blockIdx.y, t = threadIdx.x;
    if (t < 32) {
        float lv = lstab[((size_t)(t >> 2) * BHN + bh) * 4 + (t & 3)];
        float g = lv;
#pragma unroll
        for (int o = 1; o < 32; o <<= 1) g = fmaxf(g, __shfl_xor(g, o));
        f[t >> 2][t & 3] = __expf(lv - g);
    }
    __syncthreads();
    const int grp = t >> 6;
    float s = 0.f;
    if (n < 64) {
        float vsg = 0.f;
#pragma unroll
        for (int ck = 0; ck < 8; ++ck) {
            vsg += vsum_part[((size_t)ck * BHN + bh) * HDD + n];
            s += kv_part[(((size_t)ck * BHN + bh) * HDD + n) * MM + t] * f[ck][grp];
        }
        s = 0.0625f * (s + 1e-4f * vsg);
    } else if (n == 64) {
#pragma unroll
        for (int ck = 0; ck < 8; ++ck)
            s += ksum_part[((size_t)ck * BHN + bh) * MM + t] * f[ck][grp];
        s = 0.0625f * (s + 1e-4f * 4096.0f);
    }
    Bmat[((size_t)bh * 80 + n) * MM + t] = (n <= 64) ? f2bf(s) : (u16)0;
}

// ---------------- out_fused v2: QBLK=64, B-frags direct from L2, no Blds ----------------
__global__ __launch_bounds__(256) void out_fused(
    const u16* __restrict__ Qh, const u16* __restrict__ projb,
    const float* __restrict__ dq, const u16* __restrict__ Bmat,
    float* __restrict__ out)
{
    __shared__ __align__(16) u16 Qlds[64 * 64];
    __shared__ __align__(16) u16 qlds[64 * 256];
    __shared__ float red[4][64];
    const int tid = threadIdx.x, l = tid & 63, wv = tid >> 6;
    const int rt = blockIdx.x, bh = blockIdx.y;
    const size_t srowbase = (size_t)bh * SS + rt * 64;
#pragma unroll
    for (int c = 0; c < 2; ++c) {
        const int rb = wv * 16 + c * 8;
        const int r = rb + (l >> 3);
        load_lds16(Qh + (srowbase + r) * HDD + (((l & 7) ^ (r & 7)) * 8), (char*)Qlds + rb * 128);
    }
    short8 pa[4][2];
#pragma unroll
    for (int mf = 0; mf < 4; ++mf)
#pragma unroll
        for (int ks = 0; ks < 2; ++ks)
            pa[mf][ks] = *(const short8*)(projb + (wv * 64 + mf * 16 + (l & 15)) * HDD + ks * 32 + (l >> 4) * 8);
    __syncthreads();
    f32x4 u[4][4] = {};
#pragma unroll
    for (int ks = 0; ks < 2; ++ks) {
        short8 bq8[4];
#pragma unroll
        for (int nf = 0; nf < 4; ++nf) {
            const int s = nf * 16 + (l & 15);
            bq8[nf] = *(const short8*)((const char*)Qlds + s * 128 + ((ks * 64 + (l >> 4) * 16) ^ ((s & 7) << 4)));
        }
#pragma unroll
        for (int mf = 0; mf < 4; ++mf)
#pragma unroll
            for (int nf = 0; nf < 4; ++nf)
                u[mf][nf] = __builtin_amdgcn_mfma_f32_16x16x32_bf16(pa[mf][ks], bq8[nf], u[mf][nf], 0, 0, 0);
    }
#pragma unroll
    for (int nf = 0; nf < 4; ++nf) {
        float v = -3.0e38f;
#pragma unroll
        for (int mf = 0; mf < 4; ++mf)
#pragma unroll
            for (int g = 0; g < 4; ++g) v = fmaxf(v, u[mf][nf][g]);
        v = fmaxf(v, __shfl_xor(v, 16));
        v = fmaxf(v, __shfl_xor(v, 32));
        if ((l >> 4) == 0) red[wv][nf * 16 + l] = v;
    }
    __syncthreads();
#pragma unroll
    for (int nf = 0; nf < 4; ++nf) {
        const int s = nf * 16 + (l & 15);
        const float mx = fmaxf(fmaxf(red[0][s], red[1][s]), fmaxf(red[2][s], red[3][s]));
        const float dgmx = dq[srowbase + s] + mx;    // hoisted per-s bias
#pragma unroll
        for (int mf = 0; mf < 4; ++mf) {
            u16 h0 = f2bf(0.0625f * (__expf(u[mf][nf][0] - dgmx) + 1e-4f));
            u16 h1 = f2bf(0.0625f * (__expf(u[mf][nf][1] - dgmx) + 1e-4f));
            u16 h2 = f2bf(0.0625f * (__expf(u[mf][nf][2] - dgmx) + 1e-4f));
            u16 h3 = f2bf(0.0625f * (__expf(u[mf][nf][3] - dgmx) + 1e-4f));
            uint2 w; w.x = (u32)h0 | ((u32)h1 << 16); w.y = (u32)h2 | ((u32)h3 << 16);
            const int mb = (wv * 64 + mf * 16 + (l >> 4) * 4) * 2;
            *(uint2*)((char*)qlds + s * 512 + (mb ^ ((s & 7) << 4))) = w;
        }
    }
    __syncthreads();
    const u16* bbase = Bmat + (size_t)bh * 20480;
    f32x4 acc[4][2] = {};
#pragma unroll
    for (int kt = 0; kt < 8; ++kt) {
        short8 aq[4], bb[2];
#pragma unroll
        for (int mf = 0; mf < 4; ++mf) {
            const int s = mf * 16 + (l & 15);
            aq[mf] = *(const short8*)((const char*)qlds + s * 512 + ((kt * 64 + (l >> 4) * 16) ^ ((s & 7) << 4)));
        }
        bb[0] = *(const short8*)(bbase + (wv * 16 + (l & 15)) * 256 + kt * 32 + (l >> 4) * 8);
        bb[1] = *(const short8*)(bbase + (64 + (l & 15)) * 256 + kt * 32 + (l >> 4) * 8);
#pragma unroll
        for (int mf = 0; mf < 4; ++mf)
#pragma unroll
            for (int nf = 0; nf < 2; ++nf)
                acc[mf][nf] = __builtin_amdgcn_mfma_f32_16x16x32_bf16(aq[mf], bb[nf], acc[mf][nf], 0, 0, 0);
    }
    const int b = bh >> 4, h = bh & 15;
#pragma unroll
    for (int mf = 0; mf < 4; ++mf) {
#pragma unroll
        for (int g = 0; g < 4; ++g) {
            const float den = __shfl(acc[mf][1][g], (l & 48));
            const float z = 1.0f / (den + 1e-6f);
            const int s = rt * 64 + mf * 16 + (l >> 4) * 4 + g;
            out[((size_t)b * SS + s) * DD + h * HDD + wv * 16 + (l & 15)] = acc[mf][0][g] * z;
        }
    }
}

// ---------------- launcher ----------------
extern "C" void kernel_launch(void* const* d_in, const int* in_sizes, int n_in,
                              void* d_out, int out_size, void* d_ws, size_t ws_size,
                              hipStream_t stream)
{
    const float* X    = (const float*)d_in[0];
    const float* mask = (const float*)d_in[1];
    const float* Wq   = (const float*)d_in[2];
    const float* bq   = (const float*)d_in[3];
    const float* Wk   = (const float*)d_in[4];
    const float* bk   = (const float*)d_in[5];
    const float* Wv   = (const float*)d_in[6];
    const float* bv   = (const float*)d_in[7];
    const float* proj = (const float*)d_in[8];
    float* out = (float*)d_out;

    char* p = (char*)d_ws;
    u16* Xbf = (u16*)p;                            // 32 MB (aliased by kv_part after gemm1)
    float* kv_part = (float*)p; p += 33554432;
    u16* Wt = (u16*)p;    p += 6291456;
    u16* projb = (u16*)p; p += 32768;
    u16* Qh = (u16*)p;    p += 33554432;
    u16* Kh = (u16*)p;    p += 33554432;
    u16* Vt = (u16*)p;    p += 33554432;
    float* dq = (float*)p; p += 1048576;
    float* dk = (float*)p; p += 1048576;
    float* ksum_part = (float*)p; p += 524288;
    u16* Bmat = (u16*)p;  p += 2621440;
    float* vsum_part = (float*)p; p += 131072;     // [8][64][64] f32
    float* lstab = (float*)p; p += 8192;           // [8][64][4] f32
    if (ws_size < 145924096ull) return;

    hipFuncSetAttribute((const void*)gemm1_big, hipFuncAttributeMaxDynamicSharedMemorySize, 131072);
    hipFuncSetAttribute((const void*)kv_fused, hipFuncAttributeMaxDynamicSharedMemorySize, 81920);

    conv_bf16<<<2048, 256, 0, stream>>>(X, Xbf, 4194304);
    conv_w<<<dim3(48, 16), 256, 0, stream>>>(Wq, Wk, Wv, Wt);
    conv_bf16<<<16, 256, 0, stream>>>(proj, projb, 4096);
    gemm1_big<<<768, 512, 131072, stream>>>(Xbf, Wt, bq, bk, bv, mask, Qh, Kh, Vt, dq, dk);
    kv_fused<<<dim3(8, 64), 256, 81920, stream>>>(Kh, Vt, projb, dk, kv_part, ksum_part, vsum_part, lstab);
    reduceB3<<<dim3(64, 80), 256, 0, stream>>>(kv_part, ksum_part, vsum_part, lstab, Bmat);
    out_fused<<<dim3(64, 64), 256, 0, stream>>>(Qh, projb, dq, Bmat, out);
}